// Round 8
// baseline (1105.705 us; speedup 1.0000x reference)
//
#include <hip/hip_runtime.h>

#define TT 500
typedef __attribute__((ext_vector_type(8))) short short8v;
typedef __attribute__((ext_vector_type(4))) short short4v;
typedef __attribute__((ext_vector_type(4))) float float4v;
typedef unsigned short ushort;

__device__ __forceinline__ ushort f2bf(float f) {
  union { float f; unsigned u; } v; v.f = f;
  unsigned r = v.u + 0x7FFFu + ((v.u >> 16) & 1u);
  return (ushort)(r >> 16);
}
__device__ __forceinline__ float bf2f(ushort u) {
  union { unsigned u; float f; } v; v.u = ((unsigned)u) << 16;
  return v.f;
}
__device__ __forceinline__ float sigm(float x) {
  return __builtin_amdgcn_rcpf(1.f + __builtin_amdgcn_exp2f(-1.44269504088896341f * x));
}
__device__ __forceinline__ float tanh_f(float x) {
  return 1.f - 2.f * __builtin_amdgcn_rcpf(1.f + __builtin_amdgcn_exp2f(2.88539008177792682f * x));
}
__device__ __forceinline__ void bar_lds() {
  asm volatile("s_waitcnt lgkmcnt(0)\ns_barrier" ::: "memory");
}
template <int CTRL>
__device__ __forceinline__ float dppadd(float v) {
  int a = __builtin_amdgcn_update_dpp(0, __builtin_bit_cast(int, v), CTRL, 0xF, 0xF, true);
  return v + __builtin_bit_cast(float, a);
}
__device__ __forceinline__ float rsum16(float v) {
  v = dppadd<0xB1>(v);
  v = dppadd<0x4E>(v);
  v = dppadd<0x141>(v);
  v = dppadd<0x140>(v);
  return v;
}
#define MFMA __builtin_amdgcn_mfma_f32_16x16x32_bf16

// ---------------------------------------------------------------------------
__global__ __launch_bounds__(256) void conv_k(
    const float* __restrict__ W1, const float* __restrict__ W2,
    const float* __restrict__ W3, const float* __restrict__ Wih,
    const float* __restrict__ key, const float* __restrict__ Wg,
    const float* __restrict__ Wgg, ushort* __restrict__ wts)
{
  int idx = blockIdx.x * 256 + threadIdx.x;
  if (idx >= 200704) return;
  float v;
  if (idx < 32768)       v = W1[idx];
  else if (idx < 81920)  v = W2[idx - 32768];
  else if (idx < 114688) v = W3[idx - 81920];
  else if (idx < 163840) v = Wih[idx - 114688];
  else if (idx < 167936) v = key[idx - 163840];
  else {
    int j = idx - 167936, o = j >> 7, k = j & 127;
    v = (o < 128) ? Wg[o * 256 + 128 + k] : Wgg[(o - 128) * 256 + 128 + k];
  }
  wts[idx] = f2bf(v);
}

// ---------------------------------------------------------------------------
// phase1: no ds[] deferral (direct St writes after extra sync), LB(256,2).
// ---------------------------------------------------------------------------
#define XS 424
#define SS 648

__global__ __launch_bounds__(256, 2) void phase1_k(
    const int* __restrict__ a_data, const int* __restrict__ e_data,
    const float* __restrict__ qm, const float* __restrict__ semb,
    const float* __restrict__ aemb, const float* __restrict__ eemb,
    const float* __restrict__ b1, const float* __restrict__ b2,
    const float* __restrict__ b3, const float* __restrict__ bih,
    const float* __restrict__ bg, const float* __restrict__ bgg,
    const float* __restrict__ Wp, const float* __restrict__ bp,
    const float* __restrict__ Wp1, const float* __restrict__ bp1,
    const ushort* __restrict__ wts,
    ushort* __restrict__ gxb, ushort* __restrict__ xgx,
    float* __restrict__ wallb, float* __restrict__ c1b, float* __restrict__ c2b)
{
  __shared__ __align__(16) ushort sbuf[13568];
  ushort* Xl = sbuf;
  ushort* Yl = sbuf + 6784;
  ushort* St = sbuf;
  const int tid = threadIdx.x;
  const int b = blockIdx.x >> 5, chunk = blockIdx.x & 31;
  const int t0 = chunk * 16;
  const int NT = (TT - t0 < 16) ? (TT - t0) : 16;
  const ushort* w1b  = wts;
  const ushort* w2b  = wts + 32768;
  const ushort* w3b  = wts + 81920;
  const ushort* wihb = wts + 114688;
  const ushort* keyb = wts + 163840;
  const ushort* wgb  = wts + 167936;

  // ---- stage 0: X via ballot-compressed sparse gather
  {
    const int tok = tid >> 4, l16 = tid & 15;
    const int tsrc = (tok < NT) ? tok : (NT - 1);
    const int gt = b * TT + t0 + tsrc;
    const int e = e_data[gt], a = a_data[gt];
    const float* qrow = qm + (size_t)e * 101;
    float qv[7];
#pragma unroll
    for (int i = 0; i < 7; ++i) {
      int s = l16 + 16 * i;
      qv[i] = (s < 101) ? qrow[s] : 0.f;
    }
    const float* sbase = semb + l16 * 8;
    float4v acc0 = {0,0,0,0}, acc1 = {0,0,0,0};
    float cnt = 0.f;
#pragma unroll
    for (int i = 0; i < 7; ++i) {
      unsigned long long bal = __ballot(qv[i] != 0.f);
      unsigned m = (unsigned)((bal >> (tid & 48)) & 0xFFFFull);
      cnt += (float)__popc(m);
      while (m) {
        int s = 16 * i + __builtin_ctz(m);
        m &= m - 1;
        acc0 += *(const float4v*)(sbase + s * 128);
        acc1 += *(const float4v*)(sbase + s * 128 + 4);
      }
    }
    float inv = 1.f / fmaxf(cnt, 1.f);
    ushort* xr = Xl + tok * XS + l16 * 8;
#pragma unroll
    for (int r = 0; r < 4; ++r) { xr[r] = f2bf(acc0[r] * inv); xr[4 + r] = f2bf(acc1[r] * inv); }
    const float* ee = eemb + (size_t)e * 128 + l16 * 8;
    const float* ae = aemb + a * 128 + l16 * 8;
    ushort* xe = Xl + tok * XS + 128 + l16 * 8;
    ushort* xa = Xl + tok * XS + 256 + l16 * 8;
#pragma unroll
    for (int r = 0; r < 8; ++r) { xe[r] = f2bf(ee[r]); xa[r] = f2bf(ae[r]); }
  }
  __syncthreads();

  const int w = tid >> 6, l = tid & 63, jj = l & 15, seg = l >> 4;

  // ---- c1 (reads Xl e_emb part)
  if (tid < 16) {
    int tau = tid;
    if (tau < NT) {
      const ushort* xr = Xl + tau * XS + 128;
      const float* wv = Wp + 256;
      float a0 = bp[0], a1 = 0.f, a2 = 0.f, a3 = 0.f;
      for (int j = 0; j < 128; j += 4) {
        a0 = fmaf(wv[j],     bf2f(xr[j]),     a0);
        a1 = fmaf(wv[j + 1], bf2f(xr[j + 1]), a1);
        a2 = fmaf(wv[j + 2], bf2f(xr[j + 2]), a2);
        a3 = fmaf(wv[j + 3], bf2f(xr[j + 3]), a3);
      }
      c1b[b * TT + t0 + tau] = (a0 + a1) + (a2 + a3);
    }
  }

  // ---- stage A: Y via MFMA
  short8v ax[12];
#pragma unroll
  for (int i = 0; i < 12; ++i)
    ax[i] = *(short8v*)(Xl + jj * XS + i * 32 + seg * 8);

  for (int T = w; T < 24; T += 4) {
    float4v d = {0,0,0,0};
    float bv;
    if (T < 8) {
      const ushort* Bp = w1b + (T * 16 + jj) * 256 + seg * 8;
      bv = b1[T * 16 + jj];
#pragma unroll
      for (int k = 0; k < 8; ++k)
        d = MFMA(ax[k], *(const short8v*)(Bp + k * 32), d, 0, 0, 0);
    } else if (T < 16) {
      const ushort* Bp = w2b + ((T - 8) * 16 + jj) * 384 + seg * 8;
      bv = b2[(T - 8) * 16 + jj];
#pragma unroll
      for (int k = 0; k < 12; ++k)
        d = MFMA(ax[k], *(const short8v*)(Bp + k * 32), d, 0, 0, 0);
    } else {
      const ushort* Bp = w3b + ((T - 16) * 16 + jj) * 256 + seg * 8;
      bv = b3[(T - 16) * 16 + jj];
#pragma unroll
      for (int k = 0; k < 8; ++k)
        d = MFMA(ax[4 + k], *(const short8v*)(Bp + k * 32), d, 0, 0, 0);
    }
#pragma unroll
    for (int r = 0; r < 4; ++r) {
      float y = d[r] + bv;
      Yl[(seg * 4 + r) * XS + T * 16 + jj] = f2bf(y > 0.f ? y : 0.f);
    }
  }
  __syncthreads();

  // ---- load ay regs + c2 (reads Yl se_data part)
  short8v ay[12];
#pragma unroll
  for (int i = 0; i < 12; ++i)
    ay[i] = *(short8v*)(Yl + jj * XS + i * 32 + seg * 8);

  if (tid < 16) {
    int tau = tid;
    if (tau < NT) {
      const ushort* xr = Yl + tau * XS;
      const float* wv = Wp1 + 256;
      float a0 = bp1[0], a1 = 0.f, a2 = 0.f, a3 = 0.f;
      for (int j = 0; j < 128; j += 4) {
        a0 = fmaf(wv[j],     bf2f(xr[j]),     a0);
        a1 = fmaf(wv[j + 1], bf2f(xr[j + 1]), a1);
        a2 = fmaf(wv[j + 2], bf2f(xr[j + 2]), a2);
        a3 = fmaf(wv[j + 3], bf2f(xr[j + 3]), a3);
      }
      c2b[b * TT + t0 + tau] = (a0 + a1) + (a2 + a3);
    }
  }
  __syncthreads();   // all Xl/Yl reads done -> St may overlay

  // ---- stage B: direct St / wall writes
  for (int T = w; T < 42; T += 4) {
    const ushort* Bp; int ai;
    if (T < 24)      { Bp = wihb + (T * 16 + jj) * 128 + seg * 8;        ai = 8; }
    else if (T < 40) { Bp = wgb  + ((T - 24) * 16 + jj) * 128 + seg * 8; ai = 4; }
    else             { Bp = keyb + ((T - 40) * 16 + jj) * 128 + seg * 8; ai = 0; }
    float4v d = {0,0,0,0};
#pragma unroll
    for (int k = 0; k < 4; ++k)
      d = MFMA(ay[ai + k], *(const short8v*)(Bp + k * 32), d, 0, 0, 0);
    if (T < 40) {
      float bv = (T < 24) ? bih[T * 16 + jj]
               : (T < 32) ? bg[(T - 24) * 16 + jj] : bgg[(T - 32) * 16 + jj];
      int col = (T < 24) ? (T * 16 + jj) : (384 + (T - 24) * 16 + jj);
#pragma unroll
      for (int r = 0; r < 4; ++r)
        St[(seg * 4 + r) * SS + col] = f2bf(d[r] + bv);
    } else {
#pragma unroll
      for (int r = 0; r < 4; ++r) {
        int tok = seg * 4 + r;
        if (tok < NT)
          wallb[((size_t)(b * TT + t0 + tok)) * 32 + (T - 40) * 16 + jj] = d[r];
      }
    }
  }
  __syncthreads();

  // ---- coalesced copy-out
  {
    const int tok = tid >> 4, sg = tid & 15;
    if (tok < NT) {
      size_t gt = (size_t)b * TT + t0 + tok;
#pragma unroll
      for (int p = 0; p < 3; ++p)
        *(short8v*)(gxb + gt * 384 + sg * 24 + p * 8) = *(short8v*)(St + tok * SS + sg * 24 + p * 8);
#pragma unroll
      for (int p = 0; p < 2; ++p)
        *(short8v*)(xgx + gt * 256 + sg * 16 + p * 8) = *(short8v*)(St + tok * SS + 384 + sg * 16 + p * 8);
    }
  }
}

// ---------------------------------------------------------------------------
// Fused scans, 256 threads (4 waves). Mem: 2 n-tiles/wave (halves LDS h-reads).
// GRU: 6 M-tiles/wave, 1 barrier/step.
// ---------------------------------------------------------------------------
__global__ __launch_bounds__(256, 1) void scan_k(
    const float* __restrict__ Wf, const float* __restrict__ bf_,
    const float* __restrict__ Wg, const float* __restrict__ Wgg,
    const float* __restrict__ Whh, const float* __restrict__ bhh,
    const float* __restrict__ h0v, const float* __restrict__ m0,
    const ushort* __restrict__ gxb, const ushort* __restrict__ xgx,
    const float* __restrict__ wallb,
    ushort* __restrict__ htsm, ushort* __restrict__ htsg)
{
  const int tid = threadIdx.x;
  const int w = tid >> 6, l = tid & 63, jj = l & 15, seg = l >> 4;

  if (blockIdx.x < 64) {
    // ================= memory scan =================
    const int b = blockIdx.x;
    __shared__ __align__(16) ushort h_bf[32 * 128];
    __shared__ __align__(16) ushort htb[128];
    __shared__ __align__(16) ushort LGb[128];

    int n0i[2];
    n0i[0] = w * 32 + seg * 4;
    n0i[1] = w * 32 + 16 + seg * 4;

    short8v afrA[2][4], aggA[2][4], aggB[2][4], alg[2][4];
    float4v bf4[2];
#pragma unroll
    for (int i = 0; i < 2; ++i) {
      const int row = w * 32 + i * 16 + jj;
#pragma unroll
      for (int ks = 0; ks < 4; ++ks) {
        const float* sA = Wf  + row * 256 + ks * 32 + seg * 8;
        const float* sB = Wg  + row * 256 + ks * 32 + seg * 8;
        const float* sC = Wgg + row * 256 + ks * 32 + seg * 8;
        const float* sD = Wf  + row * 256 + 128 + ks * 32 + seg * 8;
        short8v a, bb, c, d;
#pragma unroll
        for (int j = 0; j < 8; ++j) {
          a[j] = (short)f2bf(sA[j]); bb[j] = (short)f2bf(sB[j]);
          c[j] = (short)f2bf(sC[j]); d[j] = (short)f2bf(sD[j]);
        }
        afrA[i][ks] = a; aggA[i][ks] = bb; aggB[i][ks] = c; alg[i][ks] = d;
      }
      bf4[i] = *(const float4v*)(bf_ + n0i[i]);
    }

    // init h = m0
    float hreg[2][2][4];   // [tile][k-half][r]
#pragma unroll
    for (int i = 0; i < 2; ++i) {
#pragma unroll
      for (int nt = 0; nt < 2; ++nt) {
        int k = nt * 16 + jj;
        float4v m = *(const float4v*)(m0 + k * 128 + n0i[i]);
#pragma unroll
        for (int r = 0; r < 4; ++r) hreg[i][nt][r] = m[r];
        int p = ((n0i[i] >> 3) + k) & 15;
        short4v pk;
#pragma unroll
        for (int r = 0; r < 4; ++r) pk[r] = (short)f2bf(hreg[i][nt][r]);
        *(short4v*)(h_bf + k * 128 + p * 8 + (n0i[i] & 7)) = pk;
      }
    }
    const float* wl = wallb + (size_t)b * TT * 32;
    const ushort* xgp = xgx + (size_t)b * TT * 256;
    float wv0 = wl[jj], wv1 = wl[16 + jj];
    float wn0 = wl[32 + jj], wn1 = wl[48 + jj];
    short4v xcg[2], xcgg[2], xng[2], xngg[2];
#pragma unroll
    for (int i = 0; i < 2; ++i) {
      xcg[i]  = *(const short4v*)(xgp + n0i[i]);
      xcgg[i] = *(const short4v*)(xgp + 128 + n0i[i]);
      xng[i]  = *(const short4v*)(xgp + 256 + n0i[i]);
      xngg[i] = *(const short4v*)(xgp + 384 + n0i[i]);
    }
    // ht0 -> htb
#pragma unroll
    for (int i = 0; i < 2; ++i) {
      float4v htp;
#pragma unroll
      for (int r = 0; r < 4; ++r)
        htp[r] = rsum16(wv0 * hreg[i][0][r] + wv1 * hreg[i][1][r]);
      if (jj == 0) {
        short4v hp;
#pragma unroll
        for (int r = 0; r < 4; ++r) hp[r] = (short)f2bf(htp[r]);
        *(short4v*)(htb + n0i[i]) = hp;
      }
    }
    __syncthreads();

    for (int t = 0; t < TT - 1; ++t) {
      // ---- dist-2 global prefetch
      int tw = (t + 2 <= TT - 1) ? (t + 2) : (TT - 1);
      float wf0 = wl[tw * 32 + jj], wf1 = wl[tw * 32 + 16 + jj];
      short4v xfg[2], xfgg[2];
#pragma unroll
      for (int i = 0; i < 2; ++i) {
        xfg[i]  = *(const short4v*)(xgp + (size_t)tw * 256 + n0i[i]);
        xfgg[i] = *(const short4v*)(xgp + (size_t)tw * 256 + 128 + n0i[i]);
      }

      // ---- hoisted LDS reads
      short8v hb[4];
#pragma unroll
      for (int ks = 0; ks < 4; ++ks)
        hb[ks] = *(short8v*)(htb + ks * 32 + seg * 8);
      short8v bv0[4], bv1[4];
#pragma unroll
      for (int ks = 0; ks < 4; ++ks) {
        int g = ks * 4 + seg;
        bv0[ks] = *(short8v*)(h_bf + jj * 128 + ((g + jj) & 15) * 8);
        bv1[ks] = *(short8v*)(h_bf + (16 + jj) * 128 + ((g + 16 + jj) & 15) * 8);
      }

      // ---- u_g/u_gg (x-side folded into C-init); 4 indep chains
      float4v dg[2], gg[2];
#pragma unroll
      for (int i = 0; i < 2; ++i) {
#pragma unroll
        for (int r = 0; r < 4; ++r) { dg[i][r] = bf2f((ushort)xcg[i][r]); gg[i][r] = bf2f((ushort)xcgg[i][r]); }
      }
#pragma unroll
      for (int ks = 0; ks < 4; ++ks) {
        dg[0] = MFMA(aggA[0][ks], hb[ks], dg[0], 0, 0, 0);
        dg[1] = MFMA(aggA[1][ks], hb[ks], dg[1], 0, 0, 0);
        gg[0] = MFMA(aggB[0][ks], hb[ks], gg[0], 0, 0, 0);
        gg[1] = MFMA(aggB[1][ks], hb[ks], gg[1], 0, 0, 0);
      }

      // ---- bigC; 4 indep chains
      float4v acc[2][2];
#pragma unroll
      for (int i = 0; i < 2; ++i) { acc[i][0] = (float4v){0,0,0,0}; acc[i][1] = (float4v){0,0,0,0}; }
#pragma unroll
      for (int ks = 0; ks < 4; ++ks) {
        acc[0][0] = MFMA(afrA[0][ks], bv0[ks], acc[0][0], 0, 0, 0);
        acc[0][1] = MFMA(afrA[0][ks], bv1[ks], acc[0][1], 0, 0, 0);
        acc[1][0] = MFMA(afrA[1][ks], bv0[ks], acc[1][0], 0, 0, 0);
        acc[1][1] = MFMA(afrA[1][ks], bv1[ks], acc[1][1], 0, 0, 0);
      }

      // ---- LG
      float lgv[2][4];
#pragma unroll
      for (int i = 0; i < 2; ++i) {
#pragma unroll
        for (int r = 0; r < 4; ++r)
          lgv[i][r] = tanh_f(dg[i][r]) * sigm(gg[i][r]);
        if (jj == 0) {
          short4v lp;
#pragma unroll
          for (int r = 0; r < 4; ++r) lp[r] = (short)f2bf(lgv[i][r]);
          *(short4v*)(LGb + n0i[i]) = lp;
        }
      }
      bar_lds();  // B1

      // ---- lgw
      short8v lb[4];
#pragma unroll
      for (int ks = 0; ks < 4; ++ks)
        lb[ks] = *(short8v*)(LGb + ks * 32 + seg * 8);
      float4v dlw[2];
      dlw[0] = bf4[0]; dlw[1] = bf4[1];
#pragma unroll
      for (int ks = 0; ks < 4; ++ks) {
        dlw[0] = MFMA(alg[0][ks], lb[ks], dlw[0], 0, 0, 0);
        dlw[1] = MFMA(alg[1][ks], lb[ks], dlw[1], 0, 0, 0);
      }

      // ---- epilogue
#pragma unroll
      for (int i = 0; i < 2; ++i) {
        float4v htp = {0,0,0,0};
#pragma unroll
        for (int nt = 0; nt < 2; ++nt) {
          float wvv = nt ? wv1 : wv0;
          float wnn = nt ? wn1 : wn0;
#pragma unroll
          for (int r = 0; r < 4; ++r) {
            float gam = sigm(acc[i][nt][r] + dlw[i][r]);
            float hn = fmaf(gam, hreg[i][nt][r], wvv * lgv[i][r]);
            hreg[i][nt][r] = hn;
            htp[r] = fmaf(wnn, hn, htp[r]);
          }
          int k = nt * 16 + jj;
          int p = ((n0i[i] >> 3) + k) & 15;
          short4v pk;
#pragma unroll
          for (int r = 0; r < 4; ++r) pk[r] = (short)f2bf(hreg[i][nt][r]);
          *(short4v*)(h_bf + k * 128 + p * 8 + (n0i[i] & 7)) = pk;
        }
#pragma unroll
        for (int r = 0; r < 4; ++r) htp[r] = rsum16(htp[r]);
        if (jj == 0) {
          short4v hp;
#pragma unroll
          for (int r = 0; r < 4; ++r) hp[r] = (short)f2bf(htp[r]);
          *(short4v*)(htb + n0i[i]) = hp;
          *(short4v*)(htsm + ((size_t)b * TT + t) * 128 + n0i[i]) = hp;
        }
      }
      wv0 = wn0; wv1 = wn1; wn0 = wf0; wn1 = wf1;
#pragma unroll
      for (int i = 0; i < 2; ++i) {
        xcg[i] = xng[i]; xcgg[i] = xngg[i]; xng[i] = xfg[i]; xngg[i] = xfgg[i];
      }
      bar_lds();  // B2
    }
  } else {
    // ================= GRU: 4 waves, 6 M-tiles/wave, 1 barrier/step ==========
    const int b = blockIdx.x - 64;
    __shared__ __align__(16) ushort hb2[2][128];

    int n0i[2];
    n0i[0] = w * 32 + seg * 4;
    n0i[1] = w * 32 + 16 + seg * 4;

    short8v wfr[3][2][4];
    float4v bfr[3][2];
#pragma unroll
    for (int g = 0; g < 3; ++g) {
#pragma unroll
      for (int i = 0; i < 2; ++i) {
        int Mt = g * 8 + w * 2 + i;
#pragma unroll
        for (int ks = 0; ks < 4; ++ks) {
          const float* src = Whh + (Mt * 16 + jj) * 128 + ks * 32 + seg * 8;
          short8v tv;
#pragma unroll
          for (int j = 0; j < 8; ++j) tv[j] = (short)f2bf(src[j]);
          wfr[g][i][ks] = tv;
        }
        bfr[g][i] = *(const float4v*)(bhh + Mt * 16 + seg * 4);
      }
    }
    const ushort* gpb = gxb + (size_t)b * TT * 384;
    float4v hj4[2];
#pragma unroll
    for (int i = 0; i < 2; ++i) {
      hj4[i] = *(const float4v*)(h0v + n0i[i]);
      if (jj == 0) {
        short4v hp;
#pragma unroll
        for (int r = 0; r < 4; ++r) hp[r] = (short)f2bf(hj4[i][r]);
        *(short4v*)(&hb2[0][n0i[i]]) = hp;
      }
    }
    short4v xr_c[2], xz_c[2], xn_c[2], xr_n[2], xz_n[2], xn_n[2];
#pragma unroll
    for (int i = 0; i < 2; ++i) {
      xr_c[i] = *(const short4v*)(gpb + n0i[i]);
      xz_c[i] = *(const short4v*)(gpb + 128 + n0i[i]);
      xn_c[i] = *(const short4v*)(gpb + 256 + n0i[i]);
      xr_n[i] = *(const short4v*)(gpb + 384 + n0i[i]);
      xz_n[i] = *(const short4v*)(gpb + 512 + n0i[i]);
      xn_n[i] = *(const short4v*)(gpb + 640 + n0i[i]);
    }
    __syncthreads();

    for (int t = 0; t < TT - 1; ++t) {
      int tf = (t + 2 < TT - 1) ? (t + 2) : (TT - 2);
      const ushort* gf = gpb + (size_t)tf * 384;
      short4v xr_f[2], xz_f[2], xn_f[2];
#pragma unroll
      for (int i = 0; i < 2; ++i) {
        xr_f[i] = *(const short4v*)(gf + n0i[i]);
        xz_f[i] = *(const short4v*)(gf + 128 + n0i[i]);
        xn_f[i] = *(const short4v*)(gf + 256 + n0i[i]);
      }

      const ushort* hsrc = hb2[t & 1];
      short8v bfrg[4];
#pragma unroll
      for (int ks = 0; ks < 4; ++ks)
        bfrg[ks] = *(short8v*)(hsrc + ks * 32 + seg * 8);

      float4v a[3][2];
#pragma unroll
      for (int g = 0; g < 3; ++g) { a[g][0] = bfr[g][0]; a[g][1] = bfr[g][1]; }
#pragma unroll
      for (int ks = 0; ks < 4; ++ks) {
#pragma unroll
        for (int g = 0; g < 3; ++g) {
          a[g][0] = MFMA(wfr[g][0][ks], bfrg[ks], a[g][0], 0, 0, 0);
          a[g][1] = MFMA(wfr[g][1][ks], bfrg[ks], a[g][1], 0, 0, 0);
        }
      }

      ushort* hdst = (ushort*)hb2[(t + 1) & 1];
#pragma unroll
      for (int i = 0; i < 2; ++i) {
        short4v hp;
#pragma unroll
        for (int r = 0; r < 4; ++r) {
          float rr = sigm(bf2f((ushort)xr_c[i][r]) + a[0][i][r]);
          float zz = sigm(bf2f((ushort)xz_c[i][r]) + a[1][i][r]);
          float nn = tanh_f(bf2f((ushort)xn_c[i][r]) + rr * a[2][i][r]);
          hj4[i][r] = fmaf(1.f - zz, nn, zz * hj4[i][r]);
          hp[r] = (short)f2bf(hj4[i][r]);
        }
        if (jj == 0) {
          *(short4v*)(hdst + n0i[i]) = hp;
          *(short4v*)(htsg + ((size_t)b * TT + t) * 128 + n0i[i]) = hp;
        }
        xr_c[i] = xr_n[i]; xz_c[i] = xz_n[i]; xn_c[i] = xn_n[i];
        xr_n[i] = xr_f[i]; xz_n[i] = xz_f[i]; xn_n[i] = xn_f[i];
      }
      bar_lds();
    }
  }
}

// ---------------------------------------------------------------------------
__global__ __launch_bounds__(256) void combine_k(
    const ushort* __restrict__ htsg, const ushort* __restrict__ htsm,
    const float* __restrict__ c1b, const float* __restrict__ c2b,
    const float* __restrict__ Wp, const float* __restrict__ Wp1,
    float* __restrict__ out)
{
  const int b = blockIdx.x;
  const int wv = threadIdx.x >> 6;
  const int lane = threadIdx.x & 63;
  const float w0 = Wp[lane], w1 = Wp[64 + lane], w2 = Wp[128 + lane], w3 = Wp[192 + lane];
  const float v0 = Wp1[lane], v1 = Wp1[64 + lane], v2 = Wp1[128 + lane], v3 = Wp1[192 + lane];
  if (threadIdx.x == 0) out[(size_t)b * TT] = 0.f;
  for (int tau = wv; tau < TT - 1; tau += 4) {
    size_t base = ((size_t)b * TT + tau) * 128;
    float hg0 = bf2f(htsg[base + lane]), hg1 = bf2f(htsg[base + 64 + lane]);
    float hm0 = bf2f(htsm[base + lane]), hm1 = bf2f(htsm[base + 64 + lane]);
    float qa = hg0 * w0 + hg1 * w1 + hm0 * w2 + hm1 * w3;
    float qb = hg0 * v0 + hg1 * v1 + hm0 * v2 + hm1 * v3;
#pragma unroll
    for (int m = 1; m < 64; m <<= 1) {
      qa += __shfl_xor(qa, m, 64);
      qb += __shfl_xor(qb, m, 64);
    }
    if (lane == 0) {
      size_t idx = (size_t)b * TT + tau + 1;
      out[idx] = sigm(qa + c1b[idx]) * sigm(qb + c2b[idx]);
    }
  }
}

// ---------------------------------------------------------------------------
extern "C" void kernel_launch(void* const* d_in, const int* in_sizes, int n_in,
                              void* d_out, int out_size, void* d_ws, size_t ws_size,
                              hipStream_t stream) {
  (void)in_sizes; (void)n_in; (void)out_size; (void)ws_size;
  const int* a_data = (const int*)d_in[1];
  const int* e_data = (const int*)d_in[2];
  const float* qm   = (const float*)d_in[4];
  const float* semb = (const float*)d_in[5];
  const float* aemb = (const float*)d_in[6];
  const float* eemb = (const float*)d_in[7];
  const float* W1 = (const float*)d_in[8];   const float* b1 = (const float*)d_in[9];
  const float* W2 = (const float*)d_in[10];  const float* b2 = (const float*)d_in[11];
  const float* W3 = (const float*)d_in[12];  const float* b3 = (const float*)d_in[13];
  const float* key = (const float*)d_in[14];
  const float* Wih = (const float*)d_in[15]; const float* Whh = (const float*)d_in[16];
  const float* bih = (const float*)d_in[17]; const float* bhh = (const float*)d_in[18];
  const float* Wg  = (const float*)d_in[19]; const float* bg  = (const float*)d_in[20];
  const float* Wgg = (const float*)d_in[21]; const float* bgg = (const float*)d_in[22];
  const float* Wf  = (const float*)d_in[23]; const float* bf_ = (const float*)d_in[24];
  const float* Wp  = (const float*)d_in[25]; const float* bp  = (const float*)d_in[26];
  const float* Wp1 = (const float*)d_in[27]; const float* bp1 = (const float*)d_in[28];
  const float* h0v = (const float*)d_in[29]; const float* m0  = (const float*)d_in[30];

  char* ws = (char*)d_ws;
  ushort* gxb  = (ushort*)(ws + 0);
  ushort* xgx  = (ushort*)(ws + 24576000);
  float* wallb = (float*)(ws + 40960000);
  ushort* htsm = (ushort*)(ws + 45056000);
  ushort* htsg = (ushort*)(ws + 53248000);
  float* c1b   = (float*)(ws + 61440000);
  float* c2b   = (float*)(ws + 61568000);
  ushort* wts  = (ushort*)(ws + 61696000);
  float* out = (float*)d_out;

  conv_k<<<dim3(784), dim3(256), 0, stream>>>(W1, W2, W3, Wih, key, Wg, Wgg, wts);
  phase1_k<<<dim3(2048), dim3(256), 0, stream>>>(
      a_data, e_data, qm, semb, aemb, eemb, b1, b2, b3, bih, bg, bgg,
      Wp, bp, Wp1, bp1, wts, gxb, xgx, wallb, c1b, c2b);
  scan_k<<<dim3(128), dim3(256), 0, stream>>>(
      Wf, bf_, Wg, Wgg, Whh, bhh, h0v, m0, gxb, xgx, wallb, htsm, htsg);
  combine_k<<<dim3(64), dim3(256), 0, stream>>>(
      htsg, htsm, c1b, c2b, Wp, Wp1, out);
}

// Round 9
// 953.956 us; speedup vs baseline: 1.1591x; 1.1591x over previous
//
#include <hip/hip_runtime.h>

#define TT 500
typedef __attribute__((ext_vector_type(8))) short short8v;
typedef __attribute__((ext_vector_type(4))) short short4v;
typedef __attribute__((ext_vector_type(4))) float float4v;
typedef unsigned short ushort;

__device__ __forceinline__ ushort f2bf(float f) {
  union { float f; unsigned u; } v; v.f = f;
  unsigned r = v.u + 0x7FFFu + ((v.u >> 16) & 1u);
  return (ushort)(r >> 16);
}
__device__ __forceinline__ float bf2f(ushort u) {
  union { unsigned u; float f; } v; v.u = ((unsigned)u) << 16;
  return v.f;
}
__device__ __forceinline__ float sigm(float x) {
  return __builtin_amdgcn_rcpf(1.f + __builtin_amdgcn_exp2f(-1.44269504088896341f * x));
}
__device__ __forceinline__ float tanh_f(float x) {
  return 1.f - 2.f * __builtin_amdgcn_rcpf(1.f + __builtin_amdgcn_exp2f(2.88539008177792682f * x));
}
__device__ __forceinline__ void bar_lds() {
  asm volatile("s_waitcnt lgkmcnt(0)\ns_barrier" ::: "memory");
}
template <int CTRL>
__device__ __forceinline__ float dppadd(float v) {
  int a = __builtin_amdgcn_update_dpp(0, __builtin_bit_cast(int, v), CTRL, 0xF, 0xF, true);
  return v + __builtin_bit_cast(float, a);
}
__device__ __forceinline__ float rsum16(float v) {
  v = dppadd<0xB1>(v);
  v = dppadd<0x4E>(v);
  v = dppadd<0x141>(v);
  v = dppadd<0x140>(v);
  return v;
}
#define MFMA __builtin_amdgcn_mfma_f32_16x16x32_bf16

// ---------------------------------------------------------------------------
__global__ __launch_bounds__(256) void conv_k(
    const float* __restrict__ W1, const float* __restrict__ W2,
    const float* __restrict__ W3, const float* __restrict__ Wih,
    const float* __restrict__ key, const float* __restrict__ Wg,
    const float* __restrict__ Wgg, ushort* __restrict__ wts)
{
  int idx = blockIdx.x * 256 + threadIdx.x;
  if (idx >= 200704) return;
  float v;
  if (idx < 32768)       v = W1[idx];
  else if (idx < 81920)  v = W2[idx - 32768];
  else if (idx < 114688) v = W3[idx - 81920];
  else if (idx < 163840) v = Wih[idx - 114688];
  else if (idx < 167936) v = key[idx - 163840];
  else {
    int j = idx - 167936, o = j >> 7, k = j & 127;
    v = (o < 128) ? Wg[o * 256 + 128 + k] : Wgg[(o - 128) * 256 + 128 + k];
  }
  wts[idx] = f2bf(v);
}

// ---------------------------------------------------------------------------
// phase1 v2: 32 tokens/block (2 token-tiles), each B-frag load feeds 2 MFMA
// chains. 1024 blocks. LDS 54 KB (2 blocks/CU).
// ---------------------------------------------------------------------------
#define XS 424
#define SS 648

__global__ __launch_bounds__(256, 2) void phase1_k(
    const int* __restrict__ a_data, const int* __restrict__ e_data,
    const float* __restrict__ qm, const float* __restrict__ semb,
    const float* __restrict__ aemb, const float* __restrict__ eemb,
    const float* __restrict__ b1, const float* __restrict__ b2,
    const float* __restrict__ b3, const float* __restrict__ bih,
    const float* __restrict__ bg, const float* __restrict__ bgg,
    const float* __restrict__ Wp, const float* __restrict__ bp,
    const float* __restrict__ Wp1, const float* __restrict__ bp1,
    const ushort* __restrict__ wts,
    ushort* __restrict__ gxb, ushort* __restrict__ xgx,
    float* __restrict__ wallb, float* __restrict__ c1b, float* __restrict__ c2b)
{
  __shared__ __align__(16) ushort sbuf[27136];   // 54,272 B
  ushort* Xl = sbuf;              // 32*424
  ushort* Yl = sbuf + 13568;      // 32*424
  ushort* St = sbuf;              // 32*648 overlay
  const int tid = threadIdx.x;
  const int b = blockIdx.x >> 4, chunk = blockIdx.x & 15;
  const int t0 = chunk * 32;
  const int NT = (TT - t0 < 32) ? (TT - t0) : 32;
  const ushort* w1b  = wts;
  const ushort* w2b  = wts + 32768;
  const ushort* w3b  = wts + 81920;
  const ushort* wihb = wts + 114688;
  const ushort* keyb = wts + 163840;
  const ushort* wgb  = wts + 167936;

  // ---- stage 0: X via ballot-compressed sparse gather (2 tokens/thread)
#pragma unroll
  for (int pass = 0; pass < 2; ++pass) {
    const int tok = (tid >> 4) + pass * 16, l16 = tid & 15;
    const int tsrc = (tok < NT) ? tok : (NT - 1);
    const int gt = b * TT + t0 + tsrc;
    const int e = e_data[gt], a = a_data[gt];
    const float* qrow = qm + (size_t)e * 101;
    float qv[7];
#pragma unroll
    for (int i = 0; i < 7; ++i) {
      int s = l16 + 16 * i;
      qv[i] = (s < 101) ? qrow[s] : 0.f;
    }
    const float* sbase = semb + l16 * 8;
    float4v acc0 = {0,0,0,0}, acc1 = {0,0,0,0};
    float cnt = 0.f;
#pragma unroll
    for (int i = 0; i < 7; ++i) {
      unsigned long long bal = __ballot(qv[i] != 0.f);
      unsigned m = (unsigned)((bal >> (tid & 48)) & 0xFFFFull);
      cnt += (float)__popc(m);
      while (m) {
        int s = 16 * i + __builtin_ctz(m);
        m &= m - 1;
        acc0 += *(const float4v*)(sbase + s * 128);
        acc1 += *(const float4v*)(sbase + s * 128 + 4);
      }
    }
    float inv = 1.f / fmaxf(cnt, 1.f);
    ushort* xr = Xl + tok * XS + l16 * 8;
#pragma unroll
    for (int r = 0; r < 4; ++r) { xr[r] = f2bf(acc0[r] * inv); xr[4 + r] = f2bf(acc1[r] * inv); }
    const float* ee = eemb + (size_t)e * 128 + l16 * 8;
    const float* ae = aemb + a * 128 + l16 * 8;
    ushort* xe = Xl + tok * XS + 128 + l16 * 8;
    ushort* xa = Xl + tok * XS + 256 + l16 * 8;
#pragma unroll
    for (int r = 0; r < 8; ++r) { xe[r] = f2bf(ee[r]); xa[r] = f2bf(ae[r]); }
  }
  __syncthreads();

  const int w = tid >> 6, l = tid & 63, jj = l & 15, seg = l >> 4;

  // ---- c1 (reads Xl e_emb part), tokens 0..31
  if (tid < 32) {
    int tau = tid;
    if (tau < NT) {
      const ushort* xr = Xl + tau * XS + 128;
      const float* wv = Wp + 256;
      float a0 = bp[0], a1 = 0.f, a2 = 0.f, a3 = 0.f;
      for (int j = 0; j < 128; j += 4) {
        a0 = fmaf(wv[j],     bf2f(xr[j]),     a0);
        a1 = fmaf(wv[j + 1], bf2f(xr[j + 1]), a1);
        a2 = fmaf(wv[j + 2], bf2f(xr[j + 2]), a2);
        a3 = fmaf(wv[j + 3], bf2f(xr[j + 3]), a3);
      }
      c1b[b * TT + t0 + tau] = (a0 + a1) + (a2 + a3);
    }
  }

  // ---- stage A: Y via MFMA, dual token-tiles sharing B
  short8v axA[12], axB[12];
#pragma unroll
  for (int i = 0; i < 12; ++i) {
    axA[i] = *(short8v*)(Xl + jj * XS + i * 32 + seg * 8);
    axB[i] = *(short8v*)(Xl + (16 + jj) * XS + i * 32 + seg * 8);
  }

  for (int T = w; T < 24; T += 4) {
    float4v dA = {0,0,0,0}, dB = {0,0,0,0};
    float bv;
    if (T < 8) {
      const ushort* Bp = w1b + (T * 16 + jj) * 256 + seg * 8;
      bv = b1[T * 16 + jj];
#pragma unroll
      for (int k = 0; k < 8; ++k) {
        short8v bw = *(const short8v*)(Bp + k * 32);
        dA = MFMA(axA[k], bw, dA, 0, 0, 0);
        dB = MFMA(axB[k], bw, dB, 0, 0, 0);
      }
    } else if (T < 16) {
      const ushort* Bp = w2b + ((T - 8) * 16 + jj) * 384 + seg * 8;
      bv = b2[(T - 8) * 16 + jj];
#pragma unroll
      for (int k = 0; k < 12; ++k) {
        short8v bw = *(const short8v*)(Bp + k * 32);
        dA = MFMA(axA[k], bw, dA, 0, 0, 0);
        dB = MFMA(axB[k], bw, dB, 0, 0, 0);
      }
    } else {
      const ushort* Bp = w3b + ((T - 16) * 16 + jj) * 256 + seg * 8;
      bv = b3[(T - 16) * 16 + jj];
#pragma unroll
      for (int k = 0; k < 8; ++k) {
        short8v bw = *(const short8v*)(Bp + k * 32);
        dA = MFMA(axA[4 + k], bw, dA, 0, 0, 0);
        dB = MFMA(axB[4 + k], bw, dB, 0, 0, 0);
      }
    }
#pragma unroll
    for (int r = 0; r < 4; ++r) {
      float yA = dA[r] + bv, yB = dB[r] + bv;
      Yl[(seg * 4 + r) * XS + T * 16 + jj]        = f2bf(yA > 0.f ? yA : 0.f);
      Yl[(16 + seg * 4 + r) * XS + T * 16 + jj]   = f2bf(yB > 0.f ? yB : 0.f);
    }
  }
  __syncthreads();

  // ---- load ay regs + c2 (reads Yl se_data part)
  short8v ayA[12], ayB[12];
#pragma unroll
  for (int i = 0; i < 12; ++i) {
    ayA[i] = *(short8v*)(Yl + jj * XS + i * 32 + seg * 8);
    ayB[i] = *(short8v*)(Yl + (16 + jj) * XS + i * 32 + seg * 8);
  }

  if (tid >= 32 && tid < 64) {
    int tau = tid - 32;
    if (tau < NT) {
      const ushort* xr = Yl + tau * XS;
      const float* wv = Wp1 + 256;
      float a0 = bp1[0], a1 = 0.f, a2 = 0.f, a3 = 0.f;
      for (int j = 0; j < 128; j += 4) {
        a0 = fmaf(wv[j],     bf2f(xr[j]),     a0);
        a1 = fmaf(wv[j + 1], bf2f(xr[j + 1]), a1);
        a2 = fmaf(wv[j + 2], bf2f(xr[j + 2]), a2);
        a3 = fmaf(wv[j + 3], bf2f(xr[j + 3]), a3);
      }
      c2b[b * TT + t0 + tau] = (a0 + a1) + (a2 + a3);
    }
  }
  __syncthreads();   // all Xl/Yl reads done -> St may overlay

  // ---- stage B: dual-tile MFMAs, direct St / wall writes
  for (int T = w; T < 42; T += 4) {
    const ushort* Bp; int ai;
    if (T < 24)      { Bp = wihb + (T * 16 + jj) * 128 + seg * 8;        ai = 8; }
    else if (T < 40) { Bp = wgb  + ((T - 24) * 16 + jj) * 128 + seg * 8; ai = 4; }
    else             { Bp = keyb + ((T - 40) * 16 + jj) * 128 + seg * 8; ai = 0; }
    float4v dA = {0,0,0,0}, dB = {0,0,0,0};
#pragma unroll
    for (int k = 0; k < 4; ++k) {
      short8v bw = *(const short8v*)(Bp + k * 32);
      dA = MFMA(ayA[ai + k], bw, dA, 0, 0, 0);
      dB = MFMA(ayB[ai + k], bw, dB, 0, 0, 0);
    }
    if (T < 40) {
      float bv = (T < 24) ? bih[T * 16 + jj]
               : (T < 32) ? bg[(T - 24) * 16 + jj] : bgg[(T - 32) * 16 + jj];
      int col = (T < 24) ? (T * 16 + jj) : (384 + (T - 24) * 16 + jj);
#pragma unroll
      for (int r = 0; r < 4; ++r) {
        St[(seg * 4 + r) * SS + col]      = f2bf(dA[r] + bv);
        St[(16 + seg * 4 + r) * SS + col] = f2bf(dB[r] + bv);
      }
    } else {
#pragma unroll
      for (int r = 0; r < 4; ++r) {
        int tokA = seg * 4 + r, tokB = 16 + seg * 4 + r;
        if (tokA < NT)
          wallb[((size_t)(b * TT + t0 + tokA)) * 32 + (T - 40) * 16 + jj] = dA[r];
        if (tokB < NT)
          wallb[((size_t)(b * TT + t0 + tokB)) * 32 + (T - 40) * 16 + jj] = dB[r];
      }
    }
  }
  __syncthreads();

  // ---- coalesced copy-out (2 tokens/thread)
#pragma unroll
  for (int pass = 0; pass < 2; ++pass) {
    const int tok = (tid >> 4) + pass * 16, sg = tid & 15;
    if (tok < NT) {
      size_t gt = (size_t)b * TT + t0 + tok;
#pragma unroll
      for (int p = 0; p < 3; ++p)
        *(short8v*)(gxb + gt * 384 + sg * 24 + p * 8) = *(short8v*)(St + tok * SS + sg * 24 + p * 8);
#pragma unroll
      for (int p = 0; p < 2; ++p)
        *(short8v*)(xgx + gt * 256 + sg * 16 + p * 8) = *(short8v*)(St + tok * SS + 384 + sg * 16 + p * 8);
    }
  }
}

// ---------------------------------------------------------------------------
// Fused scans (R7 best: 512 thr, mem 2-dep chains, GRU register-update 1-bar).
// ---------------------------------------------------------------------------
__global__ __launch_bounds__(512) void scan_k(
    const float* __restrict__ Wf, const float* __restrict__ bf_,
    const float* __restrict__ Wg, const float* __restrict__ Wgg,
    const float* __restrict__ Whh, const float* __restrict__ bhh,
    const float* __restrict__ h0v, const float* __restrict__ m0,
    const ushort* __restrict__ gxb, const ushort* __restrict__ xgx,
    const float* __restrict__ wallb,
    ushort* __restrict__ htsm, ushort* __restrict__ htsg)
{
  const int tid = threadIdx.x;
  const int w = tid >> 6, l = tid & 63, jj = l & 15, seg = l >> 4;
  const int n0 = w * 16 + seg * 4;

  if (blockIdx.x < 64) {
    // ================= memory scan =================
    const int b = blockIdx.x;
    __shared__ __align__(16) ushort h_bf[32 * 128];
    __shared__ __align__(16) ushort htb[128];
    __shared__ __align__(16) ushort LGb[128];

    short8v afrA[4], aggA[4], aggB[4], alg[4];
#pragma unroll
    for (int ks = 0; ks < 4; ++ks) {
      const float* sA = Wf  + (w * 16 + jj) * 256 + ks * 32 + seg * 8;
      const float* sB = Wg  + (w * 16 + jj) * 256 + ks * 32 + seg * 8;
      const float* sC = Wgg + (w * 16 + jj) * 256 + ks * 32 + seg * 8;
      const float* sD = Wf  + (w * 16 + jj) * 256 + 128 + ks * 32 + seg * 8;
      short8v a, bb, c, d;
#pragma unroll
      for (int j = 0; j < 8; ++j) {
        a[j] = (short)f2bf(sA[j]); bb[j] = (short)f2bf(sB[j]);
        c[j] = (short)f2bf(sC[j]); d[j] = (short)f2bf(sD[j]);
      }
      afrA[ks] = a; aggA[ks] = bb; aggB[ks] = c; alg[ks] = d;
    }
    const float4v bf4 = *(const float4v*)(bf_ + n0);

    float hreg[2][4];
#pragma unroll
    for (int nt = 0; nt < 2; ++nt) {
      int k = nt * 16 + jj;
      float4v m = *(const float4v*)(m0 + k * 128 + n0);
#pragma unroll
      for (int r = 0; r < 4; ++r) hreg[nt][r] = m[r];
      int p = ((n0 >> 3) + k) & 15;
      short4v pk;
#pragma unroll
      for (int r = 0; r < 4; ++r) pk[r] = (short)f2bf(hreg[nt][r]);
      *(short4v*)(h_bf + k * 128 + p * 8 + (n0 & 7)) = pk;
    }
    const float* wl = wallb + (size_t)b * TT * 32;
    const ushort* xgp = xgx + (size_t)b * TT * 256;
    float wv0 = wl[jj], wv1 = wl[16 + jj];
    float wn0 = wl[32 + jj], wn1 = wl[48 + jj];
    short4v xcg  = *(const short4v*)(xgp + n0);
    short4v xcgg = *(const short4v*)(xgp + 128 + n0);
    short4v xng  = *(const short4v*)(xgp + 256 + n0);
    short4v xngg = *(const short4v*)(xgp + 384 + n0);
    {
      float4v htp;
#pragma unroll
      for (int r = 0; r < 4; ++r)
        htp[r] = rsum16(wv0 * hreg[0][r] + wv1 * hreg[1][r]);
      if (jj == 0) {
        short4v hp;
#pragma unroll
        for (int r = 0; r < 4; ++r) hp[r] = (short)f2bf(htp[r]);
        *(short4v*)(htb + n0) = hp;
      }
    }
    __syncthreads();

    for (int t = 0; t < TT - 1; ++t) {
      int tw = (t + 2 <= TT - 1) ? (t + 2) : (TT - 1);
      float wf0 = wl[tw * 32 + jj], wf1 = wl[tw * 32 + 16 + jj];
      short4v xfg  = *(const short4v*)(xgp + (size_t)tw * 256 + n0);
      short4v xfgg = *(const short4v*)(xgp + (size_t)tw * 256 + 128 + n0);

      short8v hb[4];
#pragma unroll
      for (int ks = 0; ks < 4; ++ks)
        hb[ks] = *(short8v*)(htb + ks * 32 + seg * 8);
      short8v bv0[4], bv1[4];
#pragma unroll
      for (int ks = 0; ks < 4; ++ks) {
        int g = ks * 4 + seg;
        bv0[ks] = *(short8v*)(h_bf + jj * 128 + ((g + jj) & 15) * 8);
        bv1[ks] = *(short8v*)(h_bf + (16 + jj) * 128 + ((g + 16 + jj) & 15) * 8);
      }

      float4v xg4, xgg4;
#pragma unroll
      for (int r = 0; r < 4; ++r) { xg4[r] = bf2f((ushort)xcg[r]); xgg4[r] = bf2f((ushort)xcgg[r]); }
      float4v dg0 = xg4, dg1 = {0,0,0,0}, gg0 = xgg4, gg1 = {0,0,0,0};
      dg0 = MFMA(aggA[0], hb[0], dg0, 0, 0, 0);
      dg0 = MFMA(aggA[1], hb[1], dg0, 0, 0, 0);
      dg1 = MFMA(aggA[2], hb[2], dg1, 0, 0, 0);
      dg1 = MFMA(aggA[3], hb[3], dg1, 0, 0, 0);
      gg0 = MFMA(aggB[0], hb[0], gg0, 0, 0, 0);
      gg0 = MFMA(aggB[1], hb[1], gg0, 0, 0, 0);
      gg1 = MFMA(aggB[2], hb[2], gg1, 0, 0, 0);
      gg1 = MFMA(aggB[3], hb[3], gg1, 0, 0, 0);

      float4v a0A = {0,0,0,0}, a0B = {0,0,0,0}, a1A = {0,0,0,0}, a1B = {0,0,0,0};
      a0A = MFMA(afrA[0], bv0[0], a0A, 0, 0, 0);
      a0A = MFMA(afrA[1], bv0[1], a0A, 0, 0, 0);
      a0B = MFMA(afrA[2], bv0[2], a0B, 0, 0, 0);
      a0B = MFMA(afrA[3], bv0[3], a0B, 0, 0, 0);
      a1A = MFMA(afrA[0], bv1[0], a1A, 0, 0, 0);
      a1A = MFMA(afrA[1], bv1[1], a1A, 0, 0, 0);
      a1B = MFMA(afrA[2], bv1[2], a1B, 0, 0, 0);
      a1B = MFMA(afrA[3], bv1[3], a1B, 0, 0, 0);

      float lgv[4];
#pragma unroll
      for (int r = 0; r < 4; ++r)
        lgv[r] = tanh_f(dg0[r] + dg1[r]) * sigm(gg0[r] + gg1[r]);
      if (jj == 0) {
        short4v lp;
#pragma unroll
        for (int r = 0; r < 4; ++r) lp[r] = (short)f2bf(lgv[r]);
        *(short4v*)(LGb + n0) = lp;
      }
      bar_lds();  // B1

      short8v lb[4];
#pragma unroll
      for (int ks = 0; ks < 4; ++ks)
        lb[ks] = *(short8v*)(LGb + ks * 32 + seg * 8);
      float4v dl0 = bf4, dl1 = {0,0,0,0};
      dl0 = MFMA(alg[0], lb[0], dl0, 0, 0, 0);
      dl0 = MFMA(alg[1], lb[1], dl0, 0, 0, 0);
      dl1 = MFMA(alg[2], lb[2], dl1, 0, 0, 0);
      dl1 = MFMA(alg[3], lb[3], dl1, 0, 0, 0);

      float4v htp = {0,0,0,0};
#pragma unroll
      for (int nt = 0; nt < 2; ++nt) {
        float wvv = nt ? wv1 : wv0;
        float wnn = nt ? wn1 : wn0;
#pragma unroll
        for (int r = 0; r < 4; ++r) {
          float a = nt ? (a1A[r] + a1B[r]) : (a0A[r] + a0B[r]);
          float gam = sigm(a + dl0[r] + dl1[r]);
          float hn = fmaf(gam, hreg[nt][r], wvv * lgv[r]);
          hreg[nt][r] = hn;
          htp[r] = fmaf(wnn, hn, htp[r]);
        }
        int k = nt * 16 + jj;
        int p = ((n0 >> 3) + k) & 15;
        short4v pk;
#pragma unroll
        for (int r = 0; r < 4; ++r) pk[r] = (short)f2bf(hreg[nt][r]);
        *(short4v*)(h_bf + k * 128 + p * 8 + (n0 & 7)) = pk;
      }
#pragma unroll
      for (int r = 0; r < 4; ++r) htp[r] = rsum16(htp[r]);
      if (jj == 0) {
        short4v hp;
#pragma unroll
        for (int r = 0; r < 4; ++r) hp[r] = (short)f2bf(htp[r]);
        *(short4v*)(htb + n0) = hp;
        *(short4v*)(htsm + ((size_t)b * TT + t) * 128 + n0) = hp;
      }
      wv0 = wn0; wv1 = wn1; wn0 = wf0; wn1 = wf1;
      xcg = xng; xcgg = xngg; xng = xfg; xngg = xfgg;
      bar_lds();  // B2
    }
  } else {
    // ================= GRU: register h-update, 1 barrier/step =================
    const int b = blockIdx.x - 64;
    __shared__ __align__(16) ushort hb2[2][128];

    short8v wfr[3][4];
    float4v bfr[3];
#pragma unroll
    for (int i = 0; i < 3; ++i) {
      int Mt = w + i * 8;
#pragma unroll
      for (int ks = 0; ks < 4; ++ks) {
        const float* src = Whh + (Mt * 16 + jj) * 128 + ks * 32 + seg * 8;
        short8v tv;
#pragma unroll
        for (int j = 0; j < 8; ++j) tv[j] = (short)f2bf(src[j]);
        wfr[i][ks] = tv;
      }
      bfr[i] = *(const float4v*)(bhh + Mt * 16 + seg * 4);
    }
    const ushort* gpb = gxb + (size_t)b * TT * 384;
    float4v hj4 = *(const float4v*)(h0v + n0);
    if (jj == 0) {
      short4v hp;
#pragma unroll
      for (int r = 0; r < 4; ++r) hp[r] = (short)f2bf(hj4[r]);
      *(short4v*)(&hb2[0][n0]) = hp;
    }
    short4v xr_c = *(const short4v*)(gpb + n0);
    short4v xz_c = *(const short4v*)(gpb + 128 + n0);
    short4v xn_c = *(const short4v*)(gpb + 256 + n0);
    short4v xr_n = *(const short4v*)(gpb + 384 + n0);
    short4v xz_n = *(const short4v*)(gpb + 512 + n0);
    short4v xn_n = *(const short4v*)(gpb + 640 + n0);
    __syncthreads();

    for (int t = 0; t < TT - 1; ++t) {
      int tf = (t + 2 < TT - 1) ? (t + 2) : (TT - 2);
      const ushort* gf = gpb + (size_t)tf * 384;
      short4v xr_f = *(const short4v*)(gf + n0);
      short4v xz_f = *(const short4v*)(gf + 128 + n0);
      short4v xn_f = *(const short4v*)(gf + 256 + n0);

      const ushort* hsrc = hb2[t & 1];
      short8v bfrg[4];
#pragma unroll
      for (int ks = 0; ks < 4; ++ks)
        bfrg[ks] = *(short8v*)(hsrc + ks * 32 + seg * 8);

      float4v a0A = bfr[0], a1A = bfr[1], a2A = bfr[2];
      float4v a0B = {0,0,0,0}, a1B = {0,0,0,0}, a2B = {0,0,0,0};
      a0A = MFMA(wfr[0][0], bfrg[0], a0A, 0, 0, 0);
      a0A = MFMA(wfr[0][1], bfrg[1], a0A, 0, 0, 0);
      a0B = MFMA(wfr[0][2], bfrg[2], a0B, 0, 0, 0);
      a0B = MFMA(wfr[0][3], bfrg[3], a0B, 0, 0, 0);
      a1A = MFMA(wfr[1][0], bfrg[0], a1A, 0, 0, 0);
      a1A = MFMA(wfr[1][1], bfrg[1], a1A, 0, 0, 0);
      a1B = MFMA(wfr[1][2], bfrg[2], a1B, 0, 0, 0);
      a1B = MFMA(wfr[1][3], bfrg[3], a1B, 0, 0, 0);
      a2A = MFMA(wfr[2][0], bfrg[0], a2A, 0, 0, 0);
      a2A = MFMA(wfr[2][1], bfrg[1], a2A, 0, 0, 0);
      a2B = MFMA(wfr[2][2], bfrg[2], a2B, 0, 0, 0);
      a2B = MFMA(wfr[2][3], bfrg[3], a2B, 0, 0, 0);

      ushort* hdst = (ushort*)hb2[(t + 1) & 1];
      short4v hp;
#pragma unroll
      for (int r = 0; r < 4; ++r) {
        float rr = sigm(bf2f((ushort)xr_c[r]) + a0A[r] + a0B[r]);
        float zz = sigm(bf2f((ushort)xz_c[r]) + a1A[r] + a1B[r]);
        float nn = tanh_f(bf2f((ushort)xn_c[r]) + rr * (a2A[r] + a2B[r]));
        hj4[r] = fmaf(1.f - zz, nn, zz * hj4[r]);
        hp[r] = (short)f2bf(hj4[r]);
      }
      if (jj == 0) {
        *(short4v*)(hdst + n0) = hp;
        *(short4v*)(htsg + ((size_t)b * TT + t) * 128 + n0) = hp;
      }
      xr_c = xr_n; xz_c = xz_n; xn_c = xn_n;
      xr_n = xr_f; xz_n = xz_f; xn_n = xn_f;
      bar_lds();
    }
  }
}

// ---------------------------------------------------------------------------
__global__ __launch_bounds__(256) void combine_k(
    const ushort* __restrict__ htsg, const ushort* __restrict__ htsm,
    const float* __restrict__ c1b, const float* __restrict__ c2b,
    const float* __restrict__ Wp, const float* __restrict__ Wp1,
    float* __restrict__ out)
{
  const int b = blockIdx.x;
  const int wv = threadIdx.x >> 6;
  const int lane = threadIdx.x & 63;
  const float w0 = Wp[lane], w1 = Wp[64 + lane], w2 = Wp[128 + lane], w3 = Wp[192 + lane];
  const float v0 = Wp1[lane], v1 = Wp1[64 + lane], v2 = Wp1[128 + lane], v3 = Wp1[192 + lane];
  if (threadIdx.x == 0) out[(size_t)b * TT] = 0.f;
  for (int tau = wv; tau < TT - 1; tau += 4) {
    size_t base = ((size_t)b * TT + tau) * 128;
    float hg0 = bf2f(htsg[base + lane]), hg1 = bf2f(htsg[base + 64 + lane]);
    float hm0 = bf2f(htsm[base + lane]), hm1 = bf2f(htsm[base + 64 + lane]);
    float qa = hg0 * w0 + hg1 * w1 + hm0 * w2 + hm1 * w3;
    float qb = hg0 * v0 + hg1 * v1 + hm0 * v2 + hm1 * v3;
#pragma unroll
    for (int m = 1; m < 64; m <<= 1) {
      qa += __shfl_xor(qa, m, 64);
      qb += __shfl_xor(qb, m, 64);
    }
    if (lane == 0) {
      size_t idx = (size_t)b * TT + tau + 1;
      out[idx] = sigm(qa + c1b[idx]) * sigm(qb + c2b[idx]);
    }
  }
}

// ---------------------------------------------------------------------------
extern "C" void kernel_launch(void* const* d_in, const int* in_sizes, int n_in,
                              void* d_out, int out_size, void* d_ws, size_t ws_size,
                              hipStream_t stream) {
  (void)in_sizes; (void)n_in; (void)out_size; (void)ws_size;
  const int* a_data = (const int*)d_in[1];
  const int* e_data = (const int*)d_in[2];
  const float* qm   = (const float*)d_in[4];
  const float* semb = (const float*)d_in[5];
  const float* aemb = (const float*)d_in[6];
  const float* eemb = (const float*)d_in[7];
  const float* W1 = (const float*)d_in[8];   const float* b1 = (const float*)d_in[9];
  const float* W2 = (const float*)d_in[10];  const float* b2 = (const float*)d_in[11];
  const float* W3 = (const float*)d_in[12];  const float* b3 = (const float*)d_in[13];
  const float* key = (const float*)d_in[14];
  const float* Wih = (const float*)d_in[15]; const float* Whh = (const float*)d_in[16];
  const float* bih = (const float*)d_in[17]; const float* bhh = (const float*)d_in[18];
  const float* Wg  = (const float*)d_in[19]; const float* bg  = (const float*)d_in[20];
  const float* Wgg = (const float*)d_in[21]; const float* bgg = (const float*)d_in[22];
  const float* Wf  = (const float*)d_in[23]; const float* bf_ = (const float*)d_in[24];
  const float* Wp  = (const float*)d_in[25]; const float* bp  = (const float*)d_in[26];
  const float* Wp1 = (const float*)d_in[27]; const float* bp1 = (const float*)d_in[28];
  const float* h0v = (const float*)d_in[29]; const float* m0  = (const float*)d_in[30];

  char* ws = (char*)d_ws;
  ushort* gxb  = (ushort*)(ws + 0);
  ushort* xgx  = (ushort*)(ws + 24576000);
  float* wallb = (float*)(ws + 40960000);
  ushort* htsm = (ushort*)(ws + 45056000);
  ushort* htsg = (ushort*)(ws + 53248000);
  float* c1b   = (float*)(ws + 61440000);
  float* c2b   = (float*)(ws + 61568000);
  ushort* wts  = (ushort*)(ws + 61696000);
  float* out = (float*)d_out;

  conv_k<<<dim3(784), dim3(256), 0, stream>>>(W1, W2, W3, Wih, key, Wg, Wgg, wts);
  phase1_k<<<dim3(1024), dim3(256), 0, stream>>>(
      a_data, e_data, qm, semb, aemb, eemb, b1, b2, b3, bih, bg, bgg,
      Wp, bp, Wp1, bp1, wts, gxb, xgx, wallb, c1b, c2b);
  scan_k<<<dim3(128), dim3(512), 0, stream>>>(
      Wf, bf_, Wg, Wgg, Whh, bhh, h0v, m0, gxb, xgx, wallb, htsm, htsg);
  combine_k<<<dim3(64), dim3(256), 0, stream>>>(
      htsg, htsm, c1b, c2b, Wp, Wp1, out);
}

// Round 10
// 949.902 us; speedup vs baseline: 1.1640x; 1.0043x over previous
//
#include <hip/hip_runtime.h>

#define TT 500
typedef __attribute__((ext_vector_type(8))) short short8v;
typedef __attribute__((ext_vector_type(4))) short short4v;
typedef __attribute__((ext_vector_type(4))) float float4v;
typedef unsigned short ushort;

__device__ __forceinline__ ushort f2bf(float f) {   // RNE (4 ops) - used off hot loops
  union { float f; unsigned u; } v; v.f = f;
  unsigned r = v.u + 0x7FFFu + ((v.u >> 16) & 1u);
  return (ushort)(r >> 16);
}
__device__ __forceinline__ ushort f2bfr(float f) {  // round-half-up (2 ops) - hot loops
  union { float f; unsigned u; } v; v.f = f;
  return (ushort)((v.u + 0x8000u) >> 16);
}
__device__ __forceinline__ float bf2f(ushort u) {
  union { unsigned u; float f; } v; v.u = ((unsigned)u) << 16;
  return v.f;
}
__device__ __forceinline__ float sigm(float x) {
  return __builtin_amdgcn_rcpf(1.f + __builtin_amdgcn_exp2f(-1.44269504088896341f * x));
}
__device__ __forceinline__ float tanh_f(float x) {
  return 1.f - 2.f * __builtin_amdgcn_rcpf(1.f + __builtin_amdgcn_exp2f(2.88539008177792682f * x));
}
__device__ __forceinline__ void bar_lds() {
  asm volatile("s_waitcnt lgkmcnt(0)\ns_barrier" ::: "memory");
}
template <int CTRL>
__device__ __forceinline__ float dppadd(float v) {
  int a = __builtin_amdgcn_update_dpp(0, __builtin_bit_cast(int, v), CTRL, 0xF, 0xF, true);
  return v + __builtin_bit_cast(float, a);
}
__device__ __forceinline__ float rsum16(float v) {
  v = dppadd<0xB1>(v);
  v = dppadd<0x4E>(v);
  v = dppadd<0x141>(v);
  v = dppadd<0x140>(v);
  return v;
}
#define MFMA __builtin_amdgcn_mfma_f32_16x16x32_bf16

// ---------------------------------------------------------------------------
__global__ __launch_bounds__(256) void conv_k(
    const float* __restrict__ W1, const float* __restrict__ W2,
    const float* __restrict__ W3, const float* __restrict__ Wih,
    const float* __restrict__ key, const float* __restrict__ Wg,
    const float* __restrict__ Wgg, ushort* __restrict__ wts)
{
  int idx = blockIdx.x * 256 + threadIdx.x;
  if (idx >= 200704) return;
  float v;
  if (idx < 32768)       v = W1[idx];
  else if (idx < 81920)  v = W2[idx - 32768];
  else if (idx < 114688) v = W3[idx - 81920];
  else if (idx < 163840) v = Wih[idx - 114688];
  else if (idx < 167936) v = key[idx - 163840];
  else {
    int j = idx - 167936, o = j >> 7, k = j & 127;
    v = (o < 128) ? Wg[o * 256 + 128 + k] : Wgg[(o - 128) * 256 + 128 + k];
  }
  wts[idx] = f2bf(v);
}

// ---------------------------------------------------------------------------
// ph_gather: stage0 only. Writes X[tok][384] bf16 into the gxb buffer
// (in-place overlay: ph_gemm reads it to LDS, later overwrites with gx).
// 2000 blocks x 256 thr, 16 tokens/block, 16 lanes/token.
// ---------------------------------------------------------------------------
__global__ __launch_bounds__(256) void ph_gather_k(
    const int* __restrict__ a_data, const int* __restrict__ e_data,
    const float* __restrict__ qm, const float* __restrict__ semb,
    const float* __restrict__ aemb, const float* __restrict__ eemb,
    ushort* __restrict__ Xg)
{
  const int tid = threadIdx.x;
  const int tok = tid >> 4, l16 = tid & 15;
  const int gt = blockIdx.x * 16 + tok;              // flat token 0..31999
  const int e = e_data[gt], a = a_data[gt];
  const float* qrow = qm + (size_t)e * 101;
  float qv[7];
#pragma unroll
  for (int i = 0; i < 7; ++i) {
    int s = l16 + 16 * i;
    qv[i] = (s < 101) ? qrow[s] : 0.f;
  }
  const float* sbase = semb + l16 * 8;
  float4v acc0 = {0,0,0,0}, acc1 = {0,0,0,0};
  float cnt = 0.f;
#pragma unroll
  for (int i = 0; i < 7; ++i) {
    unsigned long long bal = __ballot(qv[i] != 0.f);
    unsigned m = (unsigned)((bal >> (tid & 48)) & 0xFFFFull);
    cnt += (float)__popc(m);
    while (m) {
      int s = 16 * i + __builtin_ctz(m);
      m &= m - 1;
      acc0 += *(const float4v*)(sbase + s * 128);
      acc1 += *(const float4v*)(sbase + s * 128 + 4);
    }
  }
  float inv = 1.f / fmaxf(cnt, 1.f);
  ushort* xr = Xg + (size_t)gt * 384 + l16 * 8;
  const float* ee = eemb + (size_t)e * 128 + l16 * 8;
  const float* ae = aemb + a * 128 + l16 * 8;
  short4v p0, p1;
#pragma unroll
  for (int r = 0; r < 4; ++r) { p0[r] = (short)f2bf(acc0[r] * inv); p1[r] = (short)f2bf(acc1[r] * inv); }
  *(short4v*)(xr) = p0;
  *(short4v*)(xr + 4) = p1;
#pragma unroll
  for (int r = 0; r < 8; ++r) { xr[128 + r] = f2bf(ee[r]); xr[256 + r] = f2bf(ae[r]); }
}

// ---------------------------------------------------------------------------
// ph_gemm: stages A+B. Reads X from Xg (same buffer as gxb), 32 tok/block.
// ---------------------------------------------------------------------------
#define XS 424
#define SS 648

__global__ __launch_bounds__(256, 2) void ph_gemm_k(
    const float* __restrict__ b1, const float* __restrict__ b2,
    const float* __restrict__ b3, const float* __restrict__ bih,
    const float* __restrict__ bg, const float* __restrict__ bgg,
    const float* __restrict__ Wp, const float* __restrict__ bp,
    const float* __restrict__ Wp1, const float* __restrict__ bp1,
    const ushort* __restrict__ wts,
    ushort* __restrict__ gxb, ushort* __restrict__ xgx,
    float* __restrict__ wallb, float* __restrict__ c1b, float* __restrict__ c2b)
{
  __shared__ __align__(16) ushort sbuf[27136];   // 54,272 B
  ushort* Xl = sbuf;              // 32*424
  ushort* Yl = sbuf + 13568;      // 32*424
  ushort* St = sbuf;              // 32*648 overlay
  const int tid = threadIdx.x;
  const int b = blockIdx.x >> 4, chunk = blockIdx.x & 15;
  const int t0 = chunk * 32;
  const int NT = (TT - t0 < 32) ? (TT - t0) : 32;
  const ushort* w1b  = wts;
  const ushort* w2b  = wts + 32768;
  const ushort* w3b  = wts + 81920;
  const ushort* wihb = wts + 114688;
  const ushort* keyb = wts + 163840;
  const ushort* wgb  = wts + 167936;

  // ---- load X tile from global (in-place gxb overlay)
#pragma unroll
  for (int pass = 0; pass < 2; ++pass) {
    const int tok = (tid >> 4) + pass * 16, sg = tid & 15;
    const int tsrc = (tok < NT) ? tok : (NT - 1);
    size_t gt = (size_t)b * TT + t0 + tsrc;
#pragma unroll
    for (int p = 0; p < 3; ++p)
      *(short8v*)(Xl + tok * XS + sg * 24 + p * 8) = *(const short8v*)(gxb + gt * 384 + sg * 24 + p * 8);
  }
  __syncthreads();

  const int w = tid >> 6, l = tid & 63, jj = l & 15, seg = l >> 4;

  // ---- c1 (reads Xl e_emb part)
  if (tid < 32) {
    int tau = tid;
    if (tau < NT) {
      const ushort* xr = Xl + tau * XS + 128;
      const float* wv = Wp + 256;
      float a0 = bp[0], a1 = 0.f, a2 = 0.f, a3 = 0.f;
      for (int j = 0; j < 128; j += 4) {
        a0 = fmaf(wv[j],     bf2f(xr[j]),     a0);
        a1 = fmaf(wv[j + 1], bf2f(xr[j + 1]), a1);
        a2 = fmaf(wv[j + 2], bf2f(xr[j + 2]), a2);
        a3 = fmaf(wv[j + 3], bf2f(xr[j + 3]), a3);
      }
      c1b[b * TT + t0 + tau] = (a0 + a1) + (a2 + a3);
    }
  }

  // ---- stage A: Y via MFMA, dual token-tiles sharing B
  short8v axA[12], axB[12];
#pragma unroll
  for (int i = 0; i < 12; ++i) {
    axA[i] = *(short8v*)(Xl + jj * XS + i * 32 + seg * 8);
    axB[i] = *(short8v*)(Xl + (16 + jj) * XS + i * 32 + seg * 8);
  }

  for (int T = w; T < 24; T += 4) {
    float4v dA = {0,0,0,0}, dB = {0,0,0,0};
    float bv;
    if (T < 8) {
      const ushort* Bp = w1b + (T * 16 + jj) * 256 + seg * 8;
      bv = b1[T * 16 + jj];
#pragma unroll
      for (int k = 0; k < 8; ++k) {
        short8v bw = *(const short8v*)(Bp + k * 32);
        dA = MFMA(axA[k], bw, dA, 0, 0, 0);
        dB = MFMA(axB[k], bw, dB, 0, 0, 0);
      }
    } else if (T < 16) {
      const ushort* Bp = w2b + ((T - 8) * 16 + jj) * 384 + seg * 8;
      bv = b2[(T - 8) * 16 + jj];
#pragma unroll
      for (int k = 0; k < 12; ++k) {
        short8v bw = *(const short8v*)(Bp + k * 32);
        dA = MFMA(axA[k], bw, dA, 0, 0, 0);
        dB = MFMA(axB[k], bw, dB, 0, 0, 0);
      }
    } else {
      const ushort* Bp = w3b + ((T - 16) * 16 + jj) * 256 + seg * 8;
      bv = b3[(T - 16) * 16 + jj];
#pragma unroll
      for (int k = 0; k < 8; ++k) {
        short8v bw = *(const short8v*)(Bp + k * 32);
        dA = MFMA(axA[4 + k], bw, dA, 0, 0, 0);
        dB = MFMA(axB[4 + k], bw, dB, 0, 0, 0);
      }
    }
#pragma unroll
    for (int r = 0; r < 4; ++r) {
      float yA = dA[r] + bv, yB = dB[r] + bv;
      Yl[(seg * 4 + r) * XS + T * 16 + jj]      = f2bf(yA > 0.f ? yA : 0.f);
      Yl[(16 + seg * 4 + r) * XS + T * 16 + jj] = f2bf(yB > 0.f ? yB : 0.f);
    }
  }
  __syncthreads();

  // ---- load ay regs + c2 (reads Yl se_data part)
  short8v ayA[12], ayB[12];
#pragma unroll
  for (int i = 0; i < 12; ++i) {
    ayA[i] = *(short8v*)(Yl + jj * XS + i * 32 + seg * 8);
    ayB[i] = *(short8v*)(Yl + (16 + jj) * XS + i * 32 + seg * 8);
  }

  if (tid >= 32 && tid < 64) {
    int tau = tid - 32;
    if (tau < NT) {
      const ushort* xr = Yl + tau * XS;
      const float* wv = Wp1 + 256;
      float a0 = bp1[0], a1 = 0.f, a2 = 0.f, a3 = 0.f;
      for (int j = 0; j < 128; j += 4) {
        a0 = fmaf(wv[j],     bf2f(xr[j]),     a0);
        a1 = fmaf(wv[j + 1], bf2f(xr[j + 1]), a1);
        a2 = fmaf(wv[j + 2], bf2f(xr[j + 2]), a2);
        a3 = fmaf(wv[j + 3], bf2f(xr[j + 3]), a3);
      }
      c2b[b * TT + t0 + tau] = (a0 + a1) + (a2 + a3);
    }
  }
  __syncthreads();   // all Xl/Yl reads done -> St may overlay

  // ---- stage B: dual-tile MFMAs, direct St / wall writes
  for (int T = w; T < 42; T += 4) {
    const ushort* Bp; int ai;
    if (T < 24)      { Bp = wihb + (T * 16 + jj) * 128 + seg * 8;        ai = 8; }
    else if (T < 40) { Bp = wgb  + ((T - 24) * 16 + jj) * 128 + seg * 8; ai = 4; }
    else             { Bp = keyb + ((T - 40) * 16 + jj) * 128 + seg * 8; ai = 0; }
    float4v dA = {0,0,0,0}, dB = {0,0,0,0};
#pragma unroll
    for (int k = 0; k < 4; ++k) {
      short8v bw = *(const short8v*)(Bp + k * 32);
      dA = MFMA(ayA[ai + k], bw, dA, 0, 0, 0);
      dB = MFMA(ayB[ai + k], bw, dB, 0, 0, 0);
    }
    if (T < 40) {
      float bv = (T < 24) ? bih[T * 16 + jj]
               : (T < 32) ? bg[(T - 24) * 16 + jj] : bgg[(T - 32) * 16 + jj];
      int col = (T < 24) ? (T * 16 + jj) : (384 + (T - 24) * 16 + jj);
#pragma unroll
      for (int r = 0; r < 4; ++r) {
        St[(seg * 4 + r) * SS + col]      = f2bf(dA[r] + bv);
        St[(16 + seg * 4 + r) * SS + col] = f2bf(dB[r] + bv);
      }
    } else {
#pragma unroll
      for (int r = 0; r < 4; ++r) {
        int tokA = seg * 4 + r, tokB = 16 + seg * 4 + r;
        if (tokA < NT)
          wallb[((size_t)(b * TT + t0 + tokA)) * 32 + (T - 40) * 16 + jj] = dA[r];
        if (tokB < NT)
          wallb[((size_t)(b * TT + t0 + tokB)) * 32 + (T - 40) * 16 + jj] = dB[r];
      }
    }
  }
  __syncthreads();

  // ---- coalesced copy-out (overwrites Xg region with gx — reads all done)
#pragma unroll
  for (int pass = 0; pass < 2; ++pass) {
    const int tok = (tid >> 4) + pass * 16, sg = tid & 15;
    if (tok < NT) {
      size_t gt = (size_t)b * TT + t0 + tok;
#pragma unroll
      for (int p = 0; p < 3; ++p)
        *(short8v*)(gxb + gt * 384 + sg * 24 + p * 8) = *(short8v*)(St + tok * SS + sg * 24 + p * 8);
#pragma unroll
      for (int p = 0; p < 2; ++p)
        *(short8v*)(xgx + gt * 256 + sg * 16 + p * 8) = *(short8v*)(St + tok * SS + 384 + sg * 16 + p * 8);
    }
  }
}

// ---------------------------------------------------------------------------
// Fused scans (R9 + bigC reordered after LGb-write + rhu packs).
// ---------------------------------------------------------------------------
__global__ __launch_bounds__(512) void scan_k(
    const float* __restrict__ Wf, const float* __restrict__ bf_,
    const float* __restrict__ Wg, const float* __restrict__ Wgg,
    const float* __restrict__ Whh, const float* __restrict__ bhh,
    const float* __restrict__ h0v, const float* __restrict__ m0,
    const ushort* __restrict__ gxb, const ushort* __restrict__ xgx,
    const float* __restrict__ wallb,
    ushort* __restrict__ htsm, ushort* __restrict__ htsg)
{
  const int tid = threadIdx.x;
  const int w = tid >> 6, l = tid & 63, jj = l & 15, seg = l >> 4;
  const int n0 = w * 16 + seg * 4;

  if (blockIdx.x < 64) {
    // ================= memory scan =================
    const int b = blockIdx.x;
    __shared__ __align__(16) ushort h_bf[32 * 128];
    __shared__ __align__(16) ushort htb[128];
    __shared__ __align__(16) ushort LGb[128];

    short8v afrA[4], aggA[4], aggB[4], alg[4];
#pragma unroll
    for (int ks = 0; ks < 4; ++ks) {
      const float* sA = Wf  + (w * 16 + jj) * 256 + ks * 32 + seg * 8;
      const float* sB = Wg  + (w * 16 + jj) * 256 + ks * 32 + seg * 8;
      const float* sC = Wgg + (w * 16 + jj) * 256 + ks * 32 + seg * 8;
      const float* sD = Wf  + (w * 16 + jj) * 256 + 128 + ks * 32 + seg * 8;
      short8v a, bb, c, d;
#pragma unroll
      for (int j = 0; j < 8; ++j) {
        a[j] = (short)f2bf(sA[j]); bb[j] = (short)f2bf(sB[j]);
        c[j] = (short)f2bf(sC[j]); d[j] = (short)f2bf(sD[j]);
      }
      afrA[ks] = a; aggA[ks] = bb; aggB[ks] = c; alg[ks] = d;
    }
    const float4v bf4 = *(const float4v*)(bf_ + n0);

    float hreg[2][4];
#pragma unroll
    for (int nt = 0; nt < 2; ++nt) {
      int k = nt * 16 + jj;
      float4v m = *(const float4v*)(m0 + k * 128 + n0);
#pragma unroll
      for (int r = 0; r < 4; ++r) hreg[nt][r] = m[r];
      int p = ((n0 >> 3) + k) & 15;
      short4v pk;
#pragma unroll
      for (int r = 0; r < 4; ++r) pk[r] = (short)f2bf(hreg[nt][r]);
      *(short4v*)(h_bf + k * 128 + p * 8 + (n0 & 7)) = pk;
    }
    const float* wl = wallb + (size_t)b * TT * 32;
    const ushort* xgp = xgx + (size_t)b * TT * 256;
    float wv0 = wl[jj], wv1 = wl[16 + jj];
    float wn0 = wl[32 + jj], wn1 = wl[48 + jj];
    short4v xcg  = *(const short4v*)(xgp + n0);
    short4v xcgg = *(const short4v*)(xgp + 128 + n0);
    short4v xng  = *(const short4v*)(xgp + 256 + n0);
    short4v xngg = *(const short4v*)(xgp + 384 + n0);
    {
      float4v htp;
#pragma unroll
      for (int r = 0; r < 4; ++r)
        htp[r] = rsum16(wv0 * hreg[0][r] + wv1 * hreg[1][r]);
      if (jj == 0) {
        short4v hp;
#pragma unroll
        for (int r = 0; r < 4; ++r) hp[r] = (short)f2bf(htp[r]);
        *(short4v*)(htb + n0) = hp;
      }
    }
    __syncthreads();

    for (int t = 0; t < TT - 1; ++t) {
      int tw = (t + 2 <= TT - 1) ? (t + 2) : (TT - 1);
      float wf0 = wl[tw * 32 + jj], wf1 = wl[tw * 32 + 16 + jj];
      short4v xfg  = *(const short4v*)(xgp + (size_t)tw * 256 + n0);
      short4v xfgg = *(const short4v*)(xgp + (size_t)tw * 256 + 128 + n0);

      // ---- chain-first: htb -> u MFMAs -> LG -> LGb write
      short8v hb[4];
#pragma unroll
      for (int ks = 0; ks < 4; ++ks)
        hb[ks] = *(short8v*)(htb + ks * 32 + seg * 8);

      float4v xg4, xgg4;
#pragma unroll
      for (int r = 0; r < 4; ++r) { xg4[r] = bf2f((ushort)xcg[r]); xgg4[r] = bf2f((ushort)xcgg[r]); }
      float4v dg0 = xg4, dg1 = {0,0,0,0}, gg0 = xgg4, gg1 = {0,0,0,0};
      dg0 = MFMA(aggA[0], hb[0], dg0, 0, 0, 0);
      dg0 = MFMA(aggA[1], hb[1], dg0, 0, 0, 0);
      dg1 = MFMA(aggA[2], hb[2], dg1, 0, 0, 0);
      dg1 = MFMA(aggA[3], hb[3], dg1, 0, 0, 0);
      gg0 = MFMA(aggB[0], hb[0], gg0, 0, 0, 0);
      gg0 = MFMA(aggB[1], hb[1], gg0, 0, 0, 0);
      gg1 = MFMA(aggB[2], hb[2], gg1, 0, 0, 0);
      gg1 = MFMA(aggB[3], hb[3], gg1, 0, 0, 0);

      float lgv[4];
#pragma unroll
      for (int r = 0; r < 4; ++r)
        lgv[r] = tanh_f(dg0[r] + dg1[r]) * sigm(gg0[r] + gg1[r]);
      if (jj == 0) {
        short4v lp;
#pragma unroll
        for (int r = 0; r < 4; ++r) lp[r] = (short)f2bfr(lgv[r]);
        *(short4v*)(LGb + n0) = lp;
      }

      // ---- off-chain: bigC (reads h_bf, valid until epilogue) under B1 wait
      short8v bv0[4], bv1[4];
#pragma unroll
      for (int ks = 0; ks < 4; ++ks) {
        int g = ks * 4 + seg;
        bv0[ks] = *(short8v*)(h_bf + jj * 128 + ((g + jj) & 15) * 8);
        bv1[ks] = *(short8v*)(h_bf + (16 + jj) * 128 + ((g + 16 + jj) & 15) * 8);
      }
      float4v a0A = {0,0,0,0}, a0B = {0,0,0,0}, a1A = {0,0,0,0}, a1B = {0,0,0,0};
      a0A = MFMA(afrA[0], bv0[0], a0A, 0, 0, 0);
      a0A = MFMA(afrA[1], bv0[1], a0A, 0, 0, 0);
      a0B = MFMA(afrA[2], bv0[2], a0B, 0, 0, 0);
      a0B = MFMA(afrA[3], bv0[3], a0B, 0, 0, 0);
      a1A = MFMA(afrA[0], bv1[0], a1A, 0, 0, 0);
      a1A = MFMA(afrA[1], bv1[1], a1A, 0, 0, 0);
      a1B = MFMA(afrA[2], bv1[2], a1B, 0, 0, 0);
      a1B = MFMA(afrA[3], bv1[3], a1B, 0, 0, 0);
      bar_lds();  // B1

      short8v lb[4];
#pragma unroll
      for (int ks = 0; ks < 4; ++ks)
        lb[ks] = *(short8v*)(LGb + ks * 32 + seg * 8);
      float4v dl0 = bf4, dl1 = {0,0,0,0};
      dl0 = MFMA(alg[0], lb[0], dl0, 0, 0, 0);
      dl0 = MFMA(alg[1], lb[1], dl0, 0, 0, 0);
      dl1 = MFMA(alg[2], lb[2], dl1, 0, 0, 0);
      dl1 = MFMA(alg[3], lb[3], dl1, 0, 0, 0);

      float4v htp = {0,0,0,0};
#pragma unroll
      for (int nt = 0; nt < 2; ++nt) {
        float wvv = nt ? wv1 : wv0;
        float wnn = nt ? wn1 : wn0;
#pragma unroll
        for (int r = 0; r < 4; ++r) {
          float a = nt ? (a1A[r] + a1B[r]) : (a0A[r] + a0B[r]);
          float gam = sigm(a + dl0[r] + dl1[r]);
          float hn = fmaf(gam, hreg[nt][r], wvv * lgv[r]);
          hreg[nt][r] = hn;
          htp[r] = fmaf(wnn, hn, htp[r]);
        }
        int k = nt * 16 + jj;
        int p = ((n0 >> 3) + k) & 15;
        short4v pk;
#pragma unroll
        for (int r = 0; r < 4; ++r) pk[r] = (short)f2bfr(hreg[nt][r]);
        *(short4v*)(h_bf + k * 128 + p * 8 + (n0 & 7)) = pk;
      }
#pragma unroll
      for (int r = 0; r < 4; ++r) htp[r] = rsum16(htp[r]);
      if (jj == 0) {
        short4v hp;
#pragma unroll
        for (int r = 0; r < 4; ++r) hp[r] = (short)f2bfr(htp[r]);
        *(short4v*)(htb + n0) = hp;
        *(short4v*)(htsm + ((size_t)b * TT + t) * 128 + n0) = hp;
      }
      wv0 = wn0; wv1 = wn1; wn0 = wf0; wn1 = wf1;
      xcg = xng; xcgg = xngg; xng = xfg; xngg = xfgg;
      bar_lds();  // B2
    }
  } else {
    // ================= GRU: register h-update, 1 barrier/step =================
    const int b = blockIdx.x - 64;
    __shared__ __align__(16) ushort hb2[2][128];

    short8v wfr[3][4];
    float4v bfr[3];
#pragma unroll
    for (int i = 0; i < 3; ++i) {
      int Mt = w + i * 8;
#pragma unroll
      for (int ks = 0; ks < 4; ++ks) {
        const float* src = Whh + (Mt * 16 + jj) * 128 + ks * 32 + seg * 8;
        short8v tv;
#pragma unroll
        for (int j = 0; j < 8; ++j) tv[j] = (short)f2bf(src[j]);
        wfr[i][ks] = tv;
      }
      bfr[i] = *(const float4v*)(bhh + Mt * 16 + seg * 4);
    }
    const ushort* gpb = gxb + (size_t)b * TT * 384;
    float4v hj4 = *(const float4v*)(h0v + n0);
    if (jj == 0) {
      short4v hp;
#pragma unroll
      for (int r = 0; r < 4; ++r) hp[r] = (short)f2bf(hj4[r]);
      *(short4v*)(&hb2[0][n0]) = hp;
    }
    short4v xr_c = *(const short4v*)(gpb + n0);
    short4v xz_c = *(const short4v*)(gpb + 128 + n0);
    short4v xn_c = *(const short4v*)(gpb + 256 + n0);
    short4v xr_n = *(const short4v*)(gpb + 384 + n0);
    short4v xz_n = *(const short4v*)(gpb + 512 + n0);
    short4v xn_n = *(const short4v*)(gpb + 640 + n0);
    __syncthreads();

    for (int t = 0; t < TT - 1; ++t) {
      int tf = (t + 2 < TT - 1) ? (t + 2) : (TT - 2);
      const ushort* gf = gpb + (size_t)tf * 384;
      short4v xr_f = *(const short4v*)(gf + n0);
      short4v xz_f = *(const short4v*)(gf + 128 + n0);
      short4v xn_f = *(const short4v*)(gf + 256 + n0);

      const ushort* hsrc = hb2[t & 1];
      short8v bfrg[4];
#pragma unroll
      for (int ks = 0; ks < 4; ++ks)
        bfrg[ks] = *(short8v*)(hsrc + ks * 32 + seg * 8);

      float4v a0A = bfr[0], a1A = bfr[1], a2A = bfr[2];
      float4v a0B = {0,0,0,0}, a1B = {0,0,0,0}, a2B = {0,0,0,0};
      a0A = MFMA(wfr[0][0], bfrg[0], a0A, 0, 0, 0);
      a0A = MFMA(wfr[0][1], bfrg[1], a0A, 0, 0, 0);
      a0B = MFMA(wfr[0][2], bfrg[2], a0B, 0, 0, 0);
      a0B = MFMA(wfr[0][3], bfrg[3], a0B, 0, 0, 0);
      a1A = MFMA(wfr[1][0], bfrg[0], a1A, 0, 0, 0);
      a1A = MFMA(wfr[1][1], bfrg[1], a1A, 0, 0, 0);
      a1B = MFMA(wfr[1][2], bfrg[2], a1B, 0, 0, 0);
      a1B = MFMA(wfr[1][3], bfrg[3], a1B, 0, 0, 0);
      a2A = MFMA(wfr[2][0], bfrg[0], a2A, 0, 0, 0);
      a2A = MFMA(wfr[2][1], bfrg[1], a2A, 0, 0, 0);
      a2B = MFMA(wfr[2][2], bfrg[2], a2B, 0, 0, 0);
      a2B = MFMA(wfr[2][3], bfrg[3], a2B, 0, 0, 0);

      ushort* hdst = (ushort*)hb2[(t + 1) & 1];
      short4v hp;
#pragma unroll
      for (int r = 0; r < 4; ++r) {
        float rr = sigm(bf2f((ushort)xr_c[r]) + a0A[r] + a0B[r]);
        float zz = sigm(bf2f((ushort)xz_c[r]) + a1A[r] + a1B[r]);
        float nn = tanh_f(bf2f((ushort)xn_c[r]) + rr * (a2A[r] + a2B[r]));
        hj4[r] = fmaf(1.f - zz, nn, zz * hj4[r]);
        hp[r] = (short)f2bfr(hj4[r]);
      }
      if (jj == 0) {
        *(short4v*)(hdst + n0) = hp;
        *(short4v*)(htsg + ((size_t)b * TT + t) * 128 + n0) = hp;
      }
      xr_c = xr_n; xz_c = xz_n; xn_c = xn_n;
      xr_n = xr_f; xz_n = xz_f; xn_n = xn_f;
      bar_lds();
    }
  }
}

// ---------------------------------------------------------------------------
__global__ __launch_bounds__(256) void combine_k(
    const ushort* __restrict__ htsg, const ushort* __restrict__ htsm,
    const float* __restrict__ c1b, const float* __restrict__ c2b,
    const float* __restrict__ Wp, const float* __restrict__ Wp1,
    float* __restrict__ out)
{
  const int b = blockIdx.x;
  const int wv = threadIdx.x >> 6;
  const int lane = threadIdx.x & 63;
  const float w0 = Wp[lane], w1 = Wp[64 + lane], w2 = Wp[128 + lane], w3 = Wp[192 + lane];
  const float v0 = Wp1[lane], v1 = Wp1[64 + lane], v2 = Wp1[128 + lane], v3 = Wp1[192 + lane];
  if (threadIdx.x == 0) out[(size_t)b * TT] = 0.f;
  for (int tau = wv; tau < TT - 1; tau += 4) {
    size_t base = ((size_t)b * TT + tau) * 128;
    float hg0 = bf2f(htsg[base + lane]), hg1 = bf2f(htsg[base + 64 + lane]);
    float hm0 = bf2f(htsm[base + lane]), hm1 = bf2f(htsm[base + 64 + lane]);
    float qa = hg0 * w0 + hg1 * w1 + hm0 * w2 + hm1 * w3;
    float qb = hg0 * v0 + hg1 * v1 + hm0 * v2 + hm1 * v3;
#pragma unroll
    for (int m = 1; m < 64; m <<= 1) {
      qa += __shfl_xor(qa, m, 64);
      qb += __shfl_xor(qb, m, 64);
    }
    if (lane == 0) {
      size_t idx = (size_t)b * TT + tau + 1;
      out[idx] = sigm(qa + c1b[idx]) * sigm(qb + c2b[idx]);
    }
  }
}

// ---------------------------------------------------------------------------
extern "C" void kernel_launch(void* const* d_in, const int* in_sizes, int n_in,
                              void* d_out, int out_size, void* d_ws, size_t ws_size,
                              hipStream_t stream) {
  (void)in_sizes; (void)n_in; (void)out_size; (void)ws_size;
  const int* a_data = (const int*)d_in[1];
  const int* e_data = (const int*)d_in[2];
  const float* qm   = (const float*)d_in[4];
  const float* semb = (const float*)d_in[5];
  const float* aemb = (const float*)d_in[6];
  const float* eemb = (const float*)d_in[7];
  const float* W1 = (const float*)d_in[8];   const float* b1 = (const float*)d_in[9];
  const float* W2 = (const float*)d_in[10];  const float* b2 = (const float*)d_in[11];
  const float* W3 = (const float*)d_in[12];  const float* b3 = (const float*)d_in[13];
  const float* key = (const float*)d_in[14];
  const float* Wih = (const float*)d_in[15]; const float* Whh = (const float*)d_in[16];
  const float* bih = (const float*)d_in[17]; const float* bhh = (const float*)d_in[18];
  const float* Wg  = (const float*)d_in[19]; const float* bg  = (const float*)d_in[20];
  const float* Wgg = (const float*)d_in[21]; const float* bgg = (const float*)d_in[22];
  const float* Wf  = (const float*)d_in[23]; const float* bf_ = (const float*)d_in[24];
  const float* Wp  = (const float*)d_in[25]; const float* bp  = (const float*)d_in[26];
  const float* Wp1 = (const float*)d_in[27]; const float* bp1 = (const float*)d_in[28];
  const float* h0v = (const float*)d_in[29]; const float* m0  = (const float*)d_in[30];

  char* ws = (char*)d_ws;
  ushort* gxb  = (ushort*)(ws + 0);            // doubles as X staging (overlay)
  ushort* xgx  = (ushort*)(ws + 24576000);
  float* wallb = (float*)(ws + 40960000);
  ushort* htsm = (ushort*)(ws + 45056000);
  ushort* htsg = (ushort*)(ws + 53248000);
  float* c1b   = (float*)(ws + 61440000);
  float* c2b   = (float*)(ws + 61568000);
  ushort* wts  = (ushort*)(ws + 61696000);
  float* out = (float*)d_out;

  conv_k<<<dim3(784), dim3(256), 0, stream>>>(W1, W2, W3, Wih, key, Wg, Wgg, wts);
  ph_gather_k<<<dim3(2000), dim3(256), 0, stream>>>(
      a_data, e_data, qm, semb, aemb, eemb, gxb);
  ph_gemm_k<<<dim3(1024), dim3(256), 0, stream>>>(
      b1, b2, b3, bih, bg, bgg, Wp, bp, Wp1, bp1, wts,
      gxb, xgx, wallb, c1b, c2b);
  scan_k<<<dim3(128), dim3(512), 0, stream>>>(
      Wf, bf_, Wg, Wgg, Whh, bhh, h0v, m0, gxb, xgx, wallb, htsm, htsg);
  combine_k<<<dim3(64), dim3(256), 0, stream>>>(
      htsg, htsm, c1b, c2b, Wp, Wp1, out);
}

// Round 11
// 917.109 us; speedup vs baseline: 1.2056x; 1.0358x over previous
//
#include <hip/hip_runtime.h>

#define TT 500
typedef __attribute__((ext_vector_type(8))) short short8v;
typedef __attribute__((ext_vector_type(4))) short short4v;
typedef __attribute__((ext_vector_type(4))) float float4v;
typedef unsigned short ushort;

__device__ __forceinline__ ushort f2bf(float f) {
  union { float f; unsigned u; } v; v.f = f;
  unsigned r = v.u + 0x7FFFu + ((v.u >> 16) & 1u);
  return (ushort)(r >> 16);
}
__device__ __forceinline__ ushort f2bfr(float f) {
  union { float f; unsigned u; } v; v.f = f;
  return (ushort)((v.u + 0x8000u) >> 16);
}
__device__ __forceinline__ float bf2f(ushort u) {
  union { unsigned u; float f; } v; v.u = ((unsigned)u) << 16;
  return v.f;
}
__device__ __forceinline__ float sigm(float x) {
  return __builtin_amdgcn_rcpf(1.f + __builtin_amdgcn_exp2f(-1.44269504088896341f * x));
}
__device__ __forceinline__ float tanh_f(float x) {
  return 1.f - 2.f * __builtin_amdgcn_rcpf(1.f + __builtin_amdgcn_exp2f(2.88539008177792682f * x));
}
__device__ __forceinline__ void bar_lds() {
  asm volatile("s_waitcnt lgkmcnt(0)\ns_barrier" ::: "memory");
}
template <int CTRL>
__device__ __forceinline__ float dppadd(float v) {
  int a = __builtin_amdgcn_update_dpp(0, __builtin_bit_cast(int, v), CTRL, 0xF, 0xF, true);
  return v + __builtin_bit_cast(float, a);
}
__device__ __forceinline__ float rsum16(float v) {
  v = dppadd<0xB1>(v);
  v = dppadd<0x4E>(v);
  v = dppadd<0x141>(v);
  v = dppadd<0x140>(v);
  return v;
}
// producer-consumer (cross-XCD safe): relaxed spin + acquire fence
__device__ __forceinline__ void wait_flag(int* f) {
  while (__hip_atomic_load(f, __ATOMIC_RELAXED, __HIP_MEMORY_SCOPE_AGENT) == 0)
    __builtin_amdgcn_s_sleep(8);
  __builtin_amdgcn_fence(__ATOMIC_ACQUIRE, "agent");
}
#define MFMA __builtin_amdgcn_mfma_f32_16x16x32_bf16

// ---------------------------------------------------------------------------
__global__ __launch_bounds__(256) void conv_k(
    const float* __restrict__ W1, const float* __restrict__ W2,
    const float* __restrict__ W3, const float* __restrict__ Wih,
    const float* __restrict__ key, const float* __restrict__ Wg,
    const float* __restrict__ Wgg, ushort* __restrict__ wts)
{
  int idx = blockIdx.x * 256 + threadIdx.x;
  if (idx >= 200704) return;
  float v;
  if (idx < 32768)       v = W1[idx];
  else if (idx < 81920)  v = W2[idx - 32768];
  else if (idx < 114688) v = W3[idx - 81920];
  else if (idx < 163840) v = Wih[idx - 114688];
  else if (idx < 167936) v = key[idx - 163840];
  else {
    int j = idx - 167936, o = j >> 7, k = j & 127;
    v = (o < 128) ? Wg[o * 256 + 128 + k] : Wgg[(o - 128) * 256 + 128 + k];
  }
  wts[idx] = f2bf(v);
}

// ---------------------------------------------------------------------------
// mega: blocks 0..63 mem-scan(b) | 64..127 GRU(b-64) | 128..1151 phase1
// phase1 chunk-major: gi=blk-128, chunk=gi>>6, b=gi&63  -> chunk0 first.
// ---------------------------------------------------------------------------
#define XS 424
#define SS 648

__global__ __launch_bounds__(512) void mega_k(
    const int* __restrict__ a_data, const int* __restrict__ e_data,
    const float* __restrict__ qm, const float* __restrict__ semb,
    const float* __restrict__ aemb, const float* __restrict__ eemb,
    const float* __restrict__ b1, const float* __restrict__ b2,
    const float* __restrict__ b3, const float* __restrict__ bih,
    const float* __restrict__ bg, const float* __restrict__ bgg,
    const float* __restrict__ Wp, const float* __restrict__ bp,
    const float* __restrict__ Wp1, const float* __restrict__ bp1,
    const ushort* __restrict__ wts,
    const float* __restrict__ Wf, const float* __restrict__ bf_,
    const float* __restrict__ Wg, const float* __restrict__ Wgg,
    const float* __restrict__ Whh, const float* __restrict__ bhh,
    const float* __restrict__ h0v, const float* __restrict__ m0,
    ushort* __restrict__ gxb, ushort* __restrict__ xgx,
    float* __restrict__ wallb, float* __restrict__ c1b, float* __restrict__ c2b,
    ushort* __restrict__ htsm, ushort* __restrict__ htsg,
    int* __restrict__ flags)
{
  __shared__ __align__(16) ushort pool[27136];   // 54 KB union
  const int tid = threadIdx.x;
  const int w = tid >> 6, l = tid & 63, jj = l & 15, seg = l >> 4;
  const int n0 = w * 16 + seg * 4;

  if (blockIdx.x < 64) {
    // ================= memory scan =================
    const int b = blockIdx.x;
    ushort* h_bf = pool;            // 32*128
    ushort* htb  = pool + 4096;     // 128
    ushort* LGb  = pool + 4224;     // 128

    short8v afrA[4], aggA[4], aggB[4], alg[4];
#pragma unroll
    for (int ks = 0; ks < 4; ++ks) {
      const float* sA = Wf  + (w * 16 + jj) * 256 + ks * 32 + seg * 8;
      const float* sB = Wg  + (w * 16 + jj) * 256 + ks * 32 + seg * 8;
      const float* sC = Wgg + (w * 16 + jj) * 256 + ks * 32 + seg * 8;
      const float* sD = Wf  + (w * 16 + jj) * 256 + 128 + ks * 32 + seg * 8;
      short8v a, bb, c, d;
#pragma unroll
      for (int j = 0; j < 8; ++j) {
        a[j] = (short)f2bf(sA[j]); bb[j] = (short)f2bf(sB[j]);
        c[j] = (short)f2bf(sC[j]); d[j] = (short)f2bf(sD[j]);
      }
      afrA[ks] = a; aggA[ks] = bb; aggB[ks] = c; alg[ks] = d;
    }
    const float4v bf4 = *(const float4v*)(bf_ + n0);

    float hreg[2][4];
#pragma unroll
    for (int nt = 0; nt < 2; ++nt) {
      int k = nt * 16 + jj;
      float4v m = *(const float4v*)(m0 + k * 128 + n0);
#pragma unroll
      for (int r = 0; r < 4; ++r) hreg[nt][r] = m[r];
      int p = ((n0 >> 3) + k) & 15;
      short4v pk;
#pragma unroll
      for (int r = 0; r < 4; ++r) pk[r] = (short)f2bf(hreg[nt][r]);
      *(short4v*)(h_bf + k * 128 + p * 8 + (n0 & 7)) = pk;
    }
    wait_flag(flags + b);   // chunk 0 of this batch
    const float* wl = wallb + (size_t)b * TT * 32;
    const ushort* xgp = xgx + (size_t)b * TT * 256;
    float wv0 = wl[jj], wv1 = wl[16 + jj];
    float wn0 = wl[32 + jj], wn1 = wl[48 + jj];
    short4v xcg  = *(const short4v*)(xgp + n0);
    short4v xcgg = *(const short4v*)(xgp + 128 + n0);
    short4v xng  = *(const short4v*)(xgp + 256 + n0);
    short4v xngg = *(const short4v*)(xgp + 384 + n0);
    {
      float4v htp;
#pragma unroll
      for (int r = 0; r < 4; ++r)
        htp[r] = rsum16(wv0 * hreg[0][r] + wv1 * hreg[1][r]);
      if (jj == 0) {
        short4v hp;
#pragma unroll
        for (int r = 0; r < 4; ++r) hp[r] = (short)f2bf(htp[r]);
        *(short4v*)(htb + n0) = hp;
      }
    }
    __syncthreads();

    for (int t = 0; t < TT - 1; ++t) {
      int tw = (t + 2 <= TT - 1) ? (t + 2) : (TT - 1);
      if ((tw & 31) == 0) wait_flag(flags + (tw >> 5) * 64 + b);
      float wf0 = wl[tw * 32 + jj], wf1 = wl[tw * 32 + 16 + jj];
      short4v xfg  = *(const short4v*)(xgp + (size_t)tw * 256 + n0);
      short4v xfgg = *(const short4v*)(xgp + (size_t)tw * 256 + 128 + n0);

      short8v hb[4];
#pragma unroll
      for (int ks = 0; ks < 4; ++ks)
        hb[ks] = *(short8v*)(htb + ks * 32 + seg * 8);

      float4v xg4, xgg4;
#pragma unroll
      for (int r = 0; r < 4; ++r) { xg4[r] = bf2f((ushort)xcg[r]); xgg4[r] = bf2f((ushort)xcgg[r]); }
      float4v dg0 = xg4, dg1 = {0,0,0,0}, gg0 = xgg4, gg1 = {0,0,0,0};
      dg0 = MFMA(aggA[0], hb[0], dg0, 0, 0, 0);
      dg0 = MFMA(aggA[1], hb[1], dg0, 0, 0, 0);
      dg1 = MFMA(aggA[2], hb[2], dg1, 0, 0, 0);
      dg1 = MFMA(aggA[3], hb[3], dg1, 0, 0, 0);
      gg0 = MFMA(aggB[0], hb[0], gg0, 0, 0, 0);
      gg0 = MFMA(aggB[1], hb[1], gg0, 0, 0, 0);
      gg1 = MFMA(aggB[2], hb[2], gg1, 0, 0, 0);
      gg1 = MFMA(aggB[3], hb[3], gg1, 0, 0, 0);

      float lgv[4];
#pragma unroll
      for (int r = 0; r < 4; ++r)
        lgv[r] = tanh_f(dg0[r] + dg1[r]) * sigm(gg0[r] + gg1[r]);
      if (jj == 0) {
        short4v lp;
#pragma unroll
        for (int r = 0; r < 4; ++r) lp[r] = (short)f2bfr(lgv[r]);
        *(short4v*)(LGb + n0) = lp;
      }

      short8v bv0[4], bv1[4];
#pragma unroll
      for (int ks = 0; ks < 4; ++ks) {
        int g = ks * 4 + seg;
        bv0[ks] = *(short8v*)(h_bf + jj * 128 + ((g + jj) & 15) * 8);
        bv1[ks] = *(short8v*)(h_bf + (16 + jj) * 128 + ((g + 16 + jj) & 15) * 8);
      }
      float4v a0A = {0,0,0,0}, a0B = {0,0,0,0}, a1A = {0,0,0,0}, a1B = {0,0,0,0};
      a0A = MFMA(afrA[0], bv0[0], a0A, 0, 0, 0);
      a0A = MFMA(afrA[1], bv0[1], a0A, 0, 0, 0);
      a0B = MFMA(afrA[2], bv0[2], a0B, 0, 0, 0);
      a0B = MFMA(afrA[3], bv0[3], a0B, 0, 0, 0);
      a1A = MFMA(afrA[0], bv1[0], a1A, 0, 0, 0);
      a1A = MFMA(afrA[1], bv1[1], a1A, 0, 0, 0);
      a1B = MFMA(afrA[2], bv1[2], a1B, 0, 0, 0);
      a1B = MFMA(afrA[3], bv1[3], a1B, 0, 0, 0);
      bar_lds();  // B1

      short8v lb[4];
#pragma unroll
      for (int ks = 0; ks < 4; ++ks)
        lb[ks] = *(short8v*)(LGb + ks * 32 + seg * 8);
      float4v dl0 = bf4, dl1 = {0,0,0,0};
      dl0 = MFMA(alg[0], lb[0], dl0, 0, 0, 0);
      dl0 = MFMA(alg[1], lb[1], dl0, 0, 0, 0);
      dl1 = MFMA(alg[2], lb[2], dl1, 0, 0, 0);
      dl1 = MFMA(alg[3], lb[3], dl1, 0, 0, 0);

      float4v htp = {0,0,0,0};
#pragma unroll
      for (int nt = 0; nt < 2; ++nt) {
        float wvv = nt ? wv1 : wv0;
        float wnn = nt ? wn1 : wn0;
#pragma unroll
        for (int r = 0; r < 4; ++r) {
          float a = nt ? (a1A[r] + a1B[r]) : (a0A[r] + a0B[r]);
          float gam = sigm(a + dl0[r] + dl1[r]);
          float hn = fmaf(gam, hreg[nt][r], wvv * lgv[r]);
          hreg[nt][r] = hn;
          htp[r] = fmaf(wnn, hn, htp[r]);
        }
        int k = nt * 16 + jj;
        int p = ((n0 >> 3) + k) & 15;
        short4v pk;
#pragma unroll
        for (int r = 0; r < 4; ++r) pk[r] = (short)f2bfr(hreg[nt][r]);
        *(short4v*)(h_bf + k * 128 + p * 8 + (n0 & 7)) = pk;
      }
#pragma unroll
      for (int r = 0; r < 4; ++r) htp[r] = rsum16(htp[r]);
      if (jj == 0) {
        short4v hp;
#pragma unroll
        for (int r = 0; r < 4; ++r) hp[r] = (short)f2bfr(htp[r]);
        *(short4v*)(htb + n0) = hp;
        *(short4v*)(htsm + ((size_t)b * TT + t) * 128 + n0) = hp;
      }
      wv0 = wn0; wv1 = wn1; wn0 = wf0; wn1 = wf1;
      xcg = xng; xcgg = xngg; xng = xfg; xngg = xfgg;
      bar_lds();  // B2
    }
  } else if (blockIdx.x < 128) {
    // ================= GRU =================
    const int b = blockIdx.x - 64;
    ushort* hb2 = pool;   // [2][128]

    short8v wfr[3][4];
    float4v bfr[3];
#pragma unroll
    for (int i = 0; i < 3; ++i) {
      int Mt = w + i * 8;
#pragma unroll
      for (int ks = 0; ks < 4; ++ks) {
        const float* src = Whh + (Mt * 16 + jj) * 128 + ks * 32 + seg * 8;
        short8v tv;
#pragma unroll
        for (int j = 0; j < 8; ++j) tv[j] = (short)f2bf(src[j]);
        wfr[i][ks] = tv;
      }
      bfr[i] = *(const float4v*)(bhh + Mt * 16 + seg * 4);
    }
    float4v hj4 = *(const float4v*)(h0v + n0);
    if (jj == 0) {
      short4v hp;
#pragma unroll
      for (int r = 0; r < 4; ++r) hp[r] = (short)f2bf(hj4[r]);
      *(short4v*)(hb2 + n0) = hp;
    }
    wait_flag(flags + b);   // chunk 0
    const ushort* gpb = gxb + (size_t)b * TT * 384;
    short4v xr_c = *(const short4v*)(gpb + n0);
    short4v xz_c = *(const short4v*)(gpb + 128 + n0);
    short4v xn_c = *(const short4v*)(gpb + 256 + n0);
    short4v xr_n = *(const short4v*)(gpb + 384 + n0);
    short4v xz_n = *(const short4v*)(gpb + 512 + n0);
    short4v xn_n = *(const short4v*)(gpb + 640 + n0);
    __syncthreads();

    for (int t = 0; t < TT - 1; ++t) {
      int tf = (t + 2 < TT - 1) ? (t + 2) : (TT - 2);
      if ((tf & 31) == 0) wait_flag(flags + (tf >> 5) * 64 + b);
      const ushort* gf = gpb + (size_t)tf * 384;
      short4v xr_f = *(const short4v*)(gf + n0);
      short4v xz_f = *(const short4v*)(gf + 128 + n0);
      short4v xn_f = *(const short4v*)(gf + 256 + n0);

      const ushort* hsrc = hb2 + (t & 1) * 128;
      short8v bfrg[4];
#pragma unroll
      for (int ks = 0; ks < 4; ++ks)
        bfrg[ks] = *(short8v*)(hsrc + ks * 32 + seg * 8);

      float4v a0A = bfr[0], a1A = bfr[1], a2A = bfr[2];
      float4v a0B = {0,0,0,0}, a1B = {0,0,0,0}, a2B = {0,0,0,0};
      a0A = MFMA(wfr[0][0], bfrg[0], a0A, 0, 0, 0);
      a0A = MFMA(wfr[0][1], bfrg[1], a0A, 0, 0, 0);
      a0B = MFMA(wfr[0][2], bfrg[2], a0B, 0, 0, 0);
      a0B = MFMA(wfr[0][3], bfrg[3], a0B, 0, 0, 0);
      a1A = MFMA(wfr[1][0], bfrg[0], a1A, 0, 0, 0);
      a1A = MFMA(wfr[1][1], bfrg[1], a1A, 0, 0, 0);
      a1B = MFMA(wfr[1][2], bfrg[2], a1B, 0, 0, 0);
      a1B = MFMA(wfr[1][3], bfrg[3], a1B, 0, 0, 0);
      a2A = MFMA(wfr[2][0], bfrg[0], a2A, 0, 0, 0);
      a2A = MFMA(wfr[2][1], bfrg[1], a2A, 0, 0, 0);
      a2B = MFMA(wfr[2][2], bfrg[2], a2B, 0, 0, 0);
      a2B = MFMA(wfr[2][3], bfrg[3], a2B, 0, 0, 0);

      ushort* hdst = hb2 + ((t + 1) & 1) * 128;
      short4v hp;
#pragma unroll
      for (int r = 0; r < 4; ++r) {
        float rr = sigm(bf2f((ushort)xr_c[r]) + a0A[r] + a0B[r]);
        float zz = sigm(bf2f((ushort)xz_c[r]) + a1A[r] + a1B[r]);
        float nn = tanh_f(bf2f((ushort)xn_c[r]) + rr * (a2A[r] + a2B[r]));
        hj4[r] = fmaf(1.f - zz, nn, zz * hj4[r]);
        hp[r] = (short)f2bfr(hj4[r]);
      }
      if (jj == 0) {
        *(short4v*)(hdst + n0) = hp;
        *(short4v*)(htsg + ((size_t)b * TT + t) * 128 + n0) = hp;
      }
      xr_c = xr_n; xz_c = xz_n; xn_c = xn_n;
      xr_n = xr_f; xz_n = xz_f; xn_n = xn_f;
      bar_lds();
    }
  } else {
    // ================= phase1 producer (chunk-major) =================
    const int gi = blockIdx.x - 128;
    const int chunk = gi >> 6, b = gi & 63;
    const int t0 = chunk * 32;
    const int NT = (TT - t0 < 32) ? (TT - t0) : 32;
    ushort* Xl = pool;
    ushort* Yl = pool + 13568;
    ushort* St = pool;
    const ushort* w1b  = wts;
    const ushort* w2b  = wts + 32768;
    const ushort* w3b  = wts + 81920;
    const ushort* wihb = wts + 114688;
    const ushort* keyb = wts + 163840;
    const ushort* wgb  = wts + 167936;

    // ---- stage 0: gather (32 tokens, 16 lanes each)
    {
      const int tok = tid >> 4, l16 = tid & 15;
      const int tsrc = (tok < NT) ? tok : (NT - 1);
      const int gt = b * TT + t0 + tsrc;
      const int e = e_data[gt], a = a_data[gt];
      const float* qrow = qm + (size_t)e * 101;
      float qv[7];
#pragma unroll
      for (int i = 0; i < 7; ++i) {
        int s = l16 + 16 * i;
        qv[i] = (s < 101) ? qrow[s] : 0.f;
      }
      const float* sbase = semb + l16 * 8;
      float4v acc0 = {0,0,0,0}, acc1 = {0,0,0,0};
      float cnt = 0.f;
#pragma unroll
      for (int i = 0; i < 7; ++i) {
        unsigned long long bal = __ballot(qv[i] != 0.f);
        unsigned m = (unsigned)((bal >> (tid & 48)) & 0xFFFFull);
        cnt += (float)__popc(m);
        while (m) {
          int s = 16 * i + __builtin_ctz(m);
          m &= m - 1;
          acc0 += *(const float4v*)(sbase + s * 128);
          acc1 += *(const float4v*)(sbase + s * 128 + 4);
        }
      }
      float inv = 1.f / fmaxf(cnt, 1.f);
      ushort* xr = Xl + tok * XS + l16 * 8;
#pragma unroll
      for (int r = 0; r < 4; ++r) { xr[r] = f2bf(acc0[r] * inv); xr[4 + r] = f2bf(acc1[r] * inv); }
      const float* ee = eemb + (size_t)e * 128 + l16 * 8;
      const float* ae = aemb + a * 128 + l16 * 8;
#pragma unroll
      for (int r = 0; r < 8; ++r) { xr[128 + r] = f2bf(ee[r]); xr[256 + r] = f2bf(ae[r]); }
    }
    __syncthreads();

    // ---- c1
    if (tid < 32) {
      int tau = tid;
      if (tau < NT) {
        const ushort* xr = Xl + tau * XS + 128;
        const float* wv = Wp + 256;
        float a0 = bp[0], a1 = 0.f, a2 = 0.f, a3 = 0.f;
        for (int j = 0; j < 128; j += 4) {
          a0 = fmaf(wv[j],     bf2f(xr[j]),     a0);
          a1 = fmaf(wv[j + 1], bf2f(xr[j + 1]), a1);
          a2 = fmaf(wv[j + 2], bf2f(xr[j + 2]), a2);
          a3 = fmaf(wv[j + 3], bf2f(xr[j + 3]), a3);
        }
        c1b[b * TT + t0 + tau] = (a0 + a1) + (a2 + a3);
      }
    }

    // ---- stage A (8 waves, dual token-tiles)
    short8v axA[12], axB[12];
#pragma unroll
    for (int i = 0; i < 12; ++i) {
      axA[i] = *(short8v*)(Xl + jj * XS + i * 32 + seg * 8);
      axB[i] = *(short8v*)(Xl + (16 + jj) * XS + i * 32 + seg * 8);
    }

    for (int T = w; T < 24; T += 8) {
      float4v dA = {0,0,0,0}, dB = {0,0,0,0};
      float bv;
      if (T < 8) {
        const ushort* Bp = w1b + (T * 16 + jj) * 256 + seg * 8;
        bv = b1[T * 16 + jj];
#pragma unroll
        for (int k = 0; k < 8; ++k) {
          short8v bw = *(const short8v*)(Bp + k * 32);
          dA = MFMA(axA[k], bw, dA, 0, 0, 0);
          dB = MFMA(axB[k], bw, dB, 0, 0, 0);
        }
      } else if (T < 16) {
        const ushort* Bp = w2b + ((T - 8) * 16 + jj) * 384 + seg * 8;
        bv = b2[(T - 8) * 16 + jj];
#pragma unroll
        for (int k = 0; k < 12; ++k) {
          short8v bw = *(const short8v*)(Bp + k * 32);
          dA = MFMA(axA[k], bw, dA, 0, 0, 0);
          dB = MFMA(axB[k], bw, dB, 0, 0, 0);
        }
      } else {
        const ushort* Bp = w3b + ((T - 16) * 16 + jj) * 256 + seg * 8;
        bv = b3[(T - 16) * 16 + jj];
#pragma unroll
        for (int k = 0; k < 8; ++k) {
          short8v bw = *(const short8v*)(Bp + k * 32);
          dA = MFMA(axA[4 + k], bw, dA, 0, 0, 0);
          dB = MFMA(axB[4 + k], bw, dB, 0, 0, 0);
        }
      }
#pragma unroll
      for (int r = 0; r < 4; ++r) {
        float yA = dA[r] + bv, yB = dB[r] + bv;
        Yl[(seg * 4 + r) * XS + T * 16 + jj]      = f2bf(yA > 0.f ? yA : 0.f);
        Yl[(16 + seg * 4 + r) * XS + T * 16 + jj] = f2bf(yB > 0.f ? yB : 0.f);
      }
    }
    __syncthreads();

    // ---- ay regs + c2
    short8v ayA[12], ayB[12];
#pragma unroll
    for (int i = 0; i < 12; ++i) {
      ayA[i] = *(short8v*)(Yl + jj * XS + i * 32 + seg * 8);
      ayB[i] = *(short8v*)(Yl + (16 + jj) * XS + i * 32 + seg * 8);
    }
    if (tid >= 32 && tid < 64) {
      int tau = tid - 32;
      if (tau < NT) {
        const ushort* xr = Yl + tau * XS;
        const float* wv = Wp1 + 256;
        float a0 = bp1[0], a1 = 0.f, a2 = 0.f, a3 = 0.f;
        for (int j = 0; j < 128; j += 4) {
          a0 = fmaf(wv[j],     bf2f(xr[j]),     a0);
          a1 = fmaf(wv[j + 1], bf2f(xr[j + 1]), a1);
          a2 = fmaf(wv[j + 2], bf2f(xr[j + 2]), a2);
          a3 = fmaf(wv[j + 3], bf2f(xr[j + 3]), a3);
        }
        c2b[b * TT + t0 + tau] = (a0 + a1) + (a2 + a3);
      }
    }
    __syncthreads();   // Xl/Yl reads done -> St overlay

    // ---- stage B
    for (int T = w; T < 42; T += 8) {
      const ushort* Bp; int ai;
      if (T < 24)      { Bp = wihb + (T * 16 + jj) * 128 + seg * 8;        ai = 8; }
      else if (T < 40) { Bp = wgb  + ((T - 24) * 16 + jj) * 128 + seg * 8; ai = 4; }
      else             { Bp = keyb + ((T - 40) * 16 + jj) * 128 + seg * 8; ai = 0; }
      float4v dA = {0,0,0,0}, dB = {0,0,0,0};
#pragma unroll
      for (int k = 0; k < 4; ++k) {
        short8v bw = *(const short8v*)(Bp + k * 32);
        dA = MFMA(ayA[ai + k], bw, dA, 0, 0, 0);
        dB = MFMA(ayB[ai + k], bw, dB, 0, 0, 0);
      }
      if (T < 40) {
        float bv = (T < 24) ? bih[T * 16 + jj]
                 : (T < 32) ? bg[(T - 24) * 16 + jj] : bgg[(T - 32) * 16 + jj];
        int col = (T < 24) ? (T * 16 + jj) : (384 + (T - 24) * 16 + jj);
#pragma unroll
        for (int r = 0; r < 4; ++r) {
          St[(seg * 4 + r) * SS + col]      = f2bf(dA[r] + bv);
          St[(16 + seg * 4 + r) * SS + col] = f2bf(dB[r] + bv);
        }
      } else {
#pragma unroll
        for (int r = 0; r < 4; ++r) {
          int tokA = seg * 4 + r, tokB = 16 + seg * 4 + r;
          if (tokA < NT)
            wallb[((size_t)(b * TT + t0 + tokA)) * 32 + (T - 40) * 16 + jj] = dA[r];
          if (tokB < NT)
            wallb[((size_t)(b * TT + t0 + tokB)) * 32 + (T - 40) * 16 + jj] = dB[r];
        }
      }
    }
    __syncthreads();

    // ---- copy-out
    {
      const int tok = tid >> 4, sg = tid & 15;
      if (tok < NT) {
        size_t gt = (size_t)b * TT + t0 + tok;
#pragma unroll
        for (int p = 0; p < 3; ++p)
          *(short8v*)(gxb + gt * 384 + sg * 24 + p * 8) = *(short8v*)(St + tok * SS + sg * 24 + p * 8);
#pragma unroll
        for (int p = 0; p < 2; ++p)
          *(short8v*)(xgx + gt * 256 + sg * 16 + p * 8) = *(short8v*)(St + tok * SS + 384 + sg * 16 + p * 8);
      }
    }
    __syncthreads();   // drains vmcnt: all stores complete
    if (tid == 0)
      __hip_atomic_store(flags + chunk * 64 + b, 1, __ATOMIC_RELEASE, __HIP_MEMORY_SCOPE_AGENT);
  }
}

// ---------------------------------------------------------------------------
__global__ __launch_bounds__(256) void combine_k(
    const ushort* __restrict__ htsg, const ushort* __restrict__ htsm,
    const float* __restrict__ c1b, const float* __restrict__ c2b,
    const float* __restrict__ Wp, const float* __restrict__ Wp1,
    float* __restrict__ out)
{
  const int b = blockIdx.x;
  const int wv = threadIdx.x >> 6;
  const int lane = threadIdx.x & 63;
  const float w0 = Wp[lane], w1 = Wp[64 + lane], w2 = Wp[128 + lane], w3 = Wp[192 + lane];
  const float v0 = Wp1[lane], v1 = Wp1[64 + lane], v2 = Wp1[128 + lane], v3 = Wp1[192 + lane];
  if (threadIdx.x == 0) out[(size_t)b * TT] = 0.f;
  for (int tau = wv; tau < TT - 1; tau += 4) {
    size_t base = ((size_t)b * TT + tau) * 128;
    float hg0 = bf2f(htsg[base + lane]), hg1 = bf2f(htsg[base + 64 + lane]);
    float hm0 = bf2f(htsm[base + lane]), hm1 = bf2f(htsm[base + 64 + lane]);
    float qa = hg0 * w0 + hg1 * w1 + hm0 * w2 + hm1 * w3;
    float qb = hg0 * v0 + hg1 * v1 + hm0 * v2 + hm1 * v3;
#pragma unroll
    for (int m = 1; m < 64; m <<= 1) {
      qa += __shfl_xor(qa, m, 64);
      qb += __shfl_xor(qb, m, 64);
    }
    if (lane == 0) {
      size_t idx = (size_t)b * TT + tau + 1;
      out[idx] = sigm(qa + c1b[idx]) * sigm(qb + c2b[idx]);
    }
  }
}

// ---------------------------------------------------------------------------
extern "C" void kernel_launch(void* const* d_in, const int* in_sizes, int n_in,
                              void* d_out, int out_size, void* d_ws, size_t ws_size,
                              hipStream_t stream) {
  (void)in_sizes; (void)n_in; (void)out_size; (void)ws_size;
  const int* a_data = (const int*)d_in[1];
  const int* e_data = (const int*)d_in[2];
  const float* qm   = (const float*)d_in[4];
  const float* semb = (const float*)d_in[5];
  const float* aemb = (const float*)d_in[6];
  const float* eemb = (const float*)d_in[7];
  const float* W1 = (const float*)d_in[8];   const float* b1 = (const float*)d_in[9];
  const float* W2 = (const float*)d_in[10];  const float* b2 = (const float*)d_in[11];
  const float* W3 = (const float*)d_in[12];  const float* b3 = (const float*)d_in[13];
  const float* key = (const float*)d_in[14];
  const float* Wih = (const float*)d_in[15]; const float* Whh = (const float*)d_in[16];
  const float* bih = (const float*)d_in[17]; const float* bhh = (const float*)d_in[18];
  const float* Wg  = (const float*)d_in[19]; const float* bg  = (const float*)d_in[20];
  const float* Wgg = (const float*)d_in[21]; const float* bgg = (const float*)d_in[22];
  const float* Wf  = (const float*)d_in[23]; const float* bf_ = (const float*)d_in[24];
  const float* Wp  = (const float*)d_in[25]; const float* bp  = (const float*)d_in[26];
  const float* Wp1 = (const float*)d_in[27]; const float* bp1 = (const float*)d_in[28];
  const float* h0v = (const float*)d_in[29]; const float* m0  = (const float*)d_in[30];

  char* ws = (char*)d_ws;
  ushort* gxb  = (ushort*)(ws + 0);
  ushort* xgx  = (ushort*)(ws + 24576000);
  float* wallb = (float*)(ws + 40960000);
  ushort* htsm = (ushort*)(ws + 45056000);
  ushort* htsg = (ushort*)(ws + 53248000);
  float* c1b   = (float*)(ws + 61440000);
  float* c2b   = (float*)(ws + 61568000);
  ushort* wts  = (ushort*)(ws + 61696000);
  int* flags   = (int*)(ws + 62097408);        // 1024 ints
  float* out = (float*)d_out;

  hipMemsetAsync(flags, 0, 1024 * sizeof(int), stream);
  conv_k<<<dim3(784), dim3(256), 0, stream>>>(W1, W2, W3, Wih, key, Wg, Wgg, wts);
  mega_k<<<dim3(1152), dim3(512), 0, stream>>>(
      a_data, e_data, qm, semb, aemb, eemb, b1, b2, b3, bih, bg, bgg,
      Wp, bp, Wp1, bp1, wts, Wf, bf_, Wg, Wgg, Whh, bhh, h0v, m0,
      gxb, xgx, wallb, c1b, c2b, htsm, htsg, flags);
  combine_k<<<dim3(64), dim3(256), 0, stream>>>(
      htsg, htsm, c1b, c2b, Wp, Wp1, out);
}

// Round 12
// 835.406 us; speedup vs baseline: 1.3236x; 1.0978x over previous
//
#include <hip/hip_runtime.h>

#define TT 500
typedef __attribute__((ext_vector_type(8))) short short8v;
typedef __attribute__((ext_vector_type(4))) short short4v;
typedef __attribute__((ext_vector_type(4))) float float4v;
typedef unsigned short ushort;

__device__ __forceinline__ ushort f2bf(float f) {
  union { float f; unsigned u; } v; v.f = f;
  unsigned r = v.u + 0x7FFFu + ((v.u >> 16) & 1u);
  return (ushort)(r >> 16);
}
__device__ __forceinline__ ushort f2bfr(float f) {
  union { float f; unsigned u; } v; v.f = f;
  return (ushort)((v.u + 0x8000u) >> 16);
}
__device__ __forceinline__ float bf2f(ushort u) {
  union { unsigned u; float f; } v; v.u = ((unsigned)u) << 16;
  return v.f;
}
__device__ __forceinline__ float sigm(float x) {
  return __builtin_amdgcn_rcpf(1.f + __builtin_amdgcn_exp2f(-1.44269504088896341f * x));
}
__device__ __forceinline__ float tanh_f(float x) {
  return 1.f - 2.f * __builtin_amdgcn_rcpf(1.f + __builtin_amdgcn_exp2f(2.88539008177792682f * x));
}
__device__ __forceinline__ void bar_lds() {
  asm volatile("s_waitcnt lgkmcnt(0)\ns_barrier" ::: "memory");
}
template <int CTRL>
__device__ __forceinline__ float dppadd(float v) {
  int a = __builtin_amdgcn_update_dpp(0, __builtin_bit_cast(int, v), CTRL, 0xF, 0xF, true);
  return v + __builtin_bit_cast(float, a);
}
__device__ __forceinline__ float rsum16(float v) {
  v = dppadd<0xB1>(v);
  v = dppadd<0x4E>(v);
  v = dppadd<0x141>(v);
  v = dppadd<0x140>(v);
  return v;
}
__device__ __forceinline__ void wait_flag(int* f) {
  while (__hip_atomic_load(f, __ATOMIC_RELAXED, __HIP_MEMORY_SCOPE_AGENT) == 0)
    __builtin_amdgcn_s_sleep(8);
  __builtin_amdgcn_fence(__ATOMIC_ACQUIRE, "agent");
}
#define MFMA __builtin_amdgcn_mfma_f32_16x16x32_bf16

// ---------------------------------------------------------------------------
__global__ __launch_bounds__(256) void conv_k(
    const float* __restrict__ W1, const float* __restrict__ W2,
    const float* __restrict__ W3, const float* __restrict__ Wih,
    const float* __restrict__ key, const float* __restrict__ Wg,
    const float* __restrict__ Wgg, ushort* __restrict__ wts)
{
  int idx = blockIdx.x * 256 + threadIdx.x;
  if (idx >= 200704) return;
  float v;
  if (idx < 32768)       v = W1[idx];
  else if (idx < 81920)  v = W2[idx - 32768];
  else if (idx < 114688) v = W3[idx - 81920];
  else if (idx < 163840) v = Wih[idx - 114688];
  else if (idx < 167936) v = key[idx - 163840];
  else {
    int j = idx - 167936, o = j >> 7, k = j & 127;
    v = (o < 128) ? Wg[o * 256 + 128 + k] : Wgg[(o - 128) * 256 + 128 + k];
  }
  wts[idx] = f2bf(v);
}

// ---------------------------------------------------------------------------
// mega: blocks 0..63 mem-scan(b) | 64..127 GRU(b-64) | 128..1151 phase1
// Scan waves run at s_setprio 3; producers at 0.
// ---------------------------------------------------------------------------
#define XS 424
#define SS 648

__global__ __launch_bounds__(512) void mega_k(
    const int* __restrict__ a_data, const int* __restrict__ e_data,
    const float* __restrict__ qm, const float* __restrict__ semb,
    const float* __restrict__ aemb, const float* __restrict__ eemb,
    const float* __restrict__ b1, const float* __restrict__ b2,
    const float* __restrict__ b3, const float* __restrict__ bih,
    const float* __restrict__ bg, const float* __restrict__ bgg,
    const float* __restrict__ Wp, const float* __restrict__ bp,
    const float* __restrict__ Wp1, const float* __restrict__ bp1,
    const ushort* __restrict__ wts,
    const float* __restrict__ Wf, const float* __restrict__ bf_,
    const float* __restrict__ Wg, const float* __restrict__ Wgg,
    const float* __restrict__ Whh, const float* __restrict__ bhh,
    const float* __restrict__ h0v, const float* __restrict__ m0,
    ushort* __restrict__ gxb, ushort* __restrict__ xgx,
    float* __restrict__ wallb, float* __restrict__ c1b, float* __restrict__ c2b,
    ushort* __restrict__ htsm, ushort* __restrict__ htsg,
    int* __restrict__ flags)
{
  __shared__ __align__(16) ushort pool[27136];
  const int tid = threadIdx.x;
  const int w = tid >> 6, l = tid & 63, jj = l & 15, seg = l >> 4;
  const int n0 = w * 16 + seg * 4;

  if (blockIdx.x < 64) {
    // ================= memory scan =================
    __builtin_amdgcn_s_setprio(3);
    const int b = blockIdx.x;
    ushort* h_bf = pool;
    ushort* htb  = pool + 4096;
    ushort* LGb  = pool + 4224;

    short8v afrA[4], aggA[4], aggB[4], alg[4];
#pragma unroll
    for (int ks = 0; ks < 4; ++ks) {
      const float* sA = Wf  + (w * 16 + jj) * 256 + ks * 32 + seg * 8;
      const float* sB = Wg  + (w * 16 + jj) * 256 + ks * 32 + seg * 8;
      const float* sC = Wgg + (w * 16 + jj) * 256 + ks * 32 + seg * 8;
      const float* sD = Wf  + (w * 16 + jj) * 256 + 128 + ks * 32 + seg * 8;
      short8v a, bb, c, d;
#pragma unroll
      for (int j = 0; j < 8; ++j) {
        a[j] = (short)f2bf(sA[j]); bb[j] = (short)f2bf(sB[j]);
        c[j] = (short)f2bf(sC[j]); d[j] = (short)f2bf(sD[j]);
      }
      afrA[ks] = a; aggA[ks] = bb; aggB[ks] = c; alg[ks] = d;
    }
    const float4v bf4 = *(const float4v*)(bf_ + n0);

    float hreg[2][4];
#pragma unroll
    for (int nt = 0; nt < 2; ++nt) {
      int k = nt * 16 + jj;
      float4v m = *(const float4v*)(m0 + k * 128 + n0);
#pragma unroll
      for (int r = 0; r < 4; ++r) hreg[nt][r] = m[r];
      int p = ((n0 >> 3) + k) & 15;
      short4v pk;
#pragma unroll
      for (int r = 0; r < 4; ++r) pk[r] = (short)f2bf(hreg[nt][r]);
      *(short4v*)(h_bf + k * 128 + p * 8 + (n0 & 7)) = pk;
    }
    wait_flag(flags + b);
    const float* wl = wallb + (size_t)b * TT * 32;
    const ushort* xgp = xgx + (size_t)b * TT * 256;
    float wv0 = wl[jj], wv1 = wl[16 + jj];
    float wn0 = wl[32 + jj], wn1 = wl[48 + jj];
    short4v xcg  = *(const short4v*)(xgp + n0);
    short4v xcgg = *(const short4v*)(xgp + 128 + n0);
    short4v xng  = *(const short4v*)(xgp + 256 + n0);
    short4v xngg = *(const short4v*)(xgp + 384 + n0);
    {
      float4v htp;
#pragma unroll
      for (int r = 0; r < 4; ++r)
        htp[r] = rsum16(wv0 * hreg[0][r] + wv1 * hreg[1][r]);
      if (jj == 0) {
        short4v hp;
#pragma unroll
        for (int r = 0; r < 4; ++r) hp[r] = (short)f2bf(htp[r]);
        *(short4v*)(htb + n0) = hp;
      }
    }
    __syncthreads();

    for (int t = 0; t < TT - 1; ++t) {
      int tw = (t + 2 <= TT - 1) ? (t + 2) : (TT - 1);
      if ((tw & 31) == 0) wait_flag(flags + (tw >> 5) * 64 + b);
      float wf0 = wl[tw * 32 + jj], wf1 = wl[tw * 32 + 16 + jj];
      short4v xfg  = *(const short4v*)(xgp + (size_t)tw * 256 + n0);
      short4v xfgg = *(const short4v*)(xgp + (size_t)tw * 256 + 128 + n0);

      short8v hb[4];
#pragma unroll
      for (int ks = 0; ks < 4; ++ks)
        hb[ks] = *(short8v*)(htb + ks * 32 + seg * 8);

      float4v xg4, xgg4;
#pragma unroll
      for (int r = 0; r < 4; ++r) { xg4[r] = bf2f((ushort)xcg[r]); xgg4[r] = bf2f((ushort)xcgg[r]); }
      float4v dg0 = xg4, dg1 = {0,0,0,0}, gg0 = xgg4, gg1 = {0,0,0,0};
      dg0 = MFMA(aggA[0], hb[0], dg0, 0, 0, 0);
      dg0 = MFMA(aggA[1], hb[1], dg0, 0, 0, 0);
      dg1 = MFMA(aggA[2], hb[2], dg1, 0, 0, 0);
      dg1 = MFMA(aggA[3], hb[3], dg1, 0, 0, 0);
      gg0 = MFMA(aggB[0], hb[0], gg0, 0, 0, 0);
      gg0 = MFMA(aggB[1], hb[1], gg0, 0, 0, 0);
      gg1 = MFMA(aggB[2], hb[2], gg1, 0, 0, 0);
      gg1 = MFMA(aggB[3], hb[3], gg1, 0, 0, 0);

      float lgv[4];
#pragma unroll
      for (int r = 0; r < 4; ++r)
        lgv[r] = tanh_f(dg0[r] + dg1[r]) * sigm(gg0[r] + gg1[r]);
      if (jj == 0) {
        short4v lp;
#pragma unroll
        for (int r = 0; r < 4; ++r) lp[r] = (short)f2bfr(lgv[r]);
        *(short4v*)(LGb + n0) = lp;
      }

      short8v bv0[4], bv1[4];
#pragma unroll
      for (int ks = 0; ks < 4; ++ks) {
        int g = ks * 4 + seg;
        bv0[ks] = *(short8v*)(h_bf + jj * 128 + ((g + jj) & 15) * 8);
        bv1[ks] = *(short8v*)(h_bf + (16 + jj) * 128 + ((g + 16 + jj) & 15) * 8);
      }
      float4v a0A = {0,0,0,0}, a0B = {0,0,0,0}, a1A = {0,0,0,0}, a1B = {0,0,0,0};
      a0A = MFMA(afrA[0], bv0[0], a0A, 0, 0, 0);
      a0A = MFMA(afrA[1], bv0[1], a0A, 0, 0, 0);
      a0B = MFMA(afrA[2], bv0[2], a0B, 0, 0, 0);
      a0B = MFMA(afrA[3], bv0[3], a0B, 0, 0, 0);
      a1A = MFMA(afrA[0], bv1[0], a1A, 0, 0, 0);
      a1A = MFMA(afrA[1], bv1[1], a1A, 0, 0, 0);
      a1B = MFMA(afrA[2], bv1[2], a1B, 0, 0, 0);
      a1B = MFMA(afrA[3], bv1[3], a1B, 0, 0, 0);
      bar_lds();  // B1

      short8v lb[4];
#pragma unroll
      for (int ks = 0; ks < 4; ++ks)
        lb[ks] = *(short8v*)(LGb + ks * 32 + seg * 8);
      float4v dl0 = bf4, dl1 = {0,0,0,0};
      dl0 = MFMA(alg[0], lb[0], dl0, 0, 0, 0);
      dl0 = MFMA(alg[1], lb[1], dl0, 0, 0, 0);
      dl1 = MFMA(alg[2], lb[2], dl1, 0, 0, 0);
      dl1 = MFMA(alg[3], lb[3], dl1, 0, 0, 0);

      float4v htp = {0,0,0,0};
#pragma unroll
      for (int nt = 0; nt < 2; ++nt) {
        float wvv = nt ? wv1 : wv0;
        float wnn = nt ? wn1 : wn0;
#pragma unroll
        for (int r = 0; r < 4; ++r) {
          float a = nt ? (a1A[r] + a1B[r]) : (a0A[r] + a0B[r]);
          float gam = sigm(a + dl0[r] + dl1[r]);
          float hn = fmaf(gam, hreg[nt][r], wvv * lgv[r]);
          hreg[nt][r] = hn;
          htp[r] = fmaf(wnn, hn, htp[r]);
        }
        int k = nt * 16 + jj;
        int p = ((n0 >> 3) + k) & 15;
        short4v pk;
#pragma unroll
        for (int r = 0; r < 4; ++r) pk[r] = (short)f2bfr(hreg[nt][r]);
        *(short4v*)(h_bf + k * 128 + p * 8 + (n0 & 7)) = pk;
      }
#pragma unroll
      for (int r = 0; r < 4; ++r) htp[r] = rsum16(htp[r]);
      if (jj == 0) {
        short4v hp;
#pragma unroll
        for (int r = 0; r < 4; ++r) hp[r] = (short)f2bfr(htp[r]);
        *(short4v*)(htb + n0) = hp;
        *(short4v*)(htsm + ((size_t)b * TT + t) * 128 + n0) = hp;
      }
      wv0 = wn0; wv1 = wn1; wn0 = wf0; wn1 = wf1;
      xcg = xng; xcgg = xngg; xng = xfg; xngg = xfgg;
      bar_lds();  // B2
    }
  } else if (blockIdx.x < 128) {
    // ================= GRU =================
    __builtin_amdgcn_s_setprio(3);
    const int b = blockIdx.x - 64;
    ushort* hb2 = pool;

    short8v wfr[3][4];
    float4v bfr[3];
#pragma unroll
    for (int i = 0; i < 3; ++i) {
      int Mt = w + i * 8;
#pragma unroll
      for (int ks = 0; ks < 4; ++ks) {
        const float* src = Whh + (Mt * 16 + jj) * 128 + ks * 32 + seg * 8;
        short8v tv;
#pragma unroll
        for (int j = 0; j < 8; ++j) tv[j] = (short)f2bf(src[j]);
        wfr[i][ks] = tv;
      }
      bfr[i] = *(const float4v*)(bhh + Mt * 16 + seg * 4);
    }
    float4v hj4 = *(const float4v*)(h0v + n0);
    if (jj == 0) {
      short4v hp;
#pragma unroll
      for (int r = 0; r < 4; ++r) hp[r] = (short)f2bf(hj4[r]);
      *(short4v*)(hb2 + n0) = hp;
    }
    wait_flag(flags + b);
    const ushort* gpb = gxb + (size_t)b * TT * 384;
    short4v xr_c = *(const short4v*)(gpb + n0);
    short4v xz_c = *(const short4v*)(gpb + 128 + n0);
    short4v xn_c = *(const short4v*)(gpb + 256 + n0);
    short4v xr_n = *(const short4v*)(gpb + 384 + n0);
    short4v xz_n = *(const short4v*)(gpb + 512 + n0);
    short4v xn_n = *(const short4v*)(gpb + 640 + n0);
    __syncthreads();

    for (int t = 0; t < TT - 1; ++t) {
      int tf = (t + 2 < TT - 1) ? (t + 2) : (TT - 2);
      if ((tf & 31) == 0) wait_flag(flags + (tf >> 5) * 64 + b);
      const ushort* gf = gpb + (size_t)tf * 384;
      short4v xr_f = *(const short4v*)(gf + n0);
      short4v xz_f = *(const short4v*)(gf + 128 + n0);
      short4v xn_f = *(const short4v*)(gf + 256 + n0);

      const ushort* hsrc = hb2 + (t & 1) * 128;
      short8v bfrg[4];
#pragma unroll
      for (int ks = 0; ks < 4; ++ks)
        bfrg[ks] = *(short8v*)(hsrc + ks * 32 + seg * 8);

      float4v a0A = bfr[0], a1A = bfr[1], a2A = bfr[2];
      float4v a0B = {0,0,0,0}, a1B = {0,0,0,0}, a2B = {0,0,0,0};
      a0A = MFMA(wfr[0][0], bfrg[0], a0A, 0, 0, 0);
      a0A = MFMA(wfr[0][1], bfrg[1], a0A, 0, 0, 0);
      a0B = MFMA(wfr[0][2], bfrg[2], a0B, 0, 0, 0);
      a0B = MFMA(wfr[0][3], bfrg[3], a0B, 0, 0, 0);
      a1A = MFMA(wfr[1][0], bfrg[0], a1A, 0, 0, 0);
      a1A = MFMA(wfr[1][1], bfrg[1], a1A, 0, 0, 0);
      a1B = MFMA(wfr[1][2], bfrg[2], a1B, 0, 0, 0);
      a1B = MFMA(wfr[1][3], bfrg[3], a1B, 0, 0, 0);
      a2A = MFMA(wfr[2][0], bfrg[0], a2A, 0, 0, 0);
      a2A = MFMA(wfr[2][1], bfrg[1], a2A, 0, 0, 0);
      a2B = MFMA(wfr[2][2], bfrg[2], a2B, 0, 0, 0);
      a2B = MFMA(wfr[2][3], bfrg[3], a2B, 0, 0, 0);

      ushort* hdst = hb2 + ((t + 1) & 1) * 128;
      short4v hp;
#pragma unroll
      for (int r = 0; r < 4; ++r) {
        float rr = sigm(bf2f((ushort)xr_c[r]) + a0A[r] + a0B[r]);
        float zz = sigm(bf2f((ushort)xz_c[r]) + a1A[r] + a1B[r]);
        float nn = tanh_f(bf2f((ushort)xn_c[r]) + rr * (a2A[r] + a2B[r]));
        hj4[r] = fmaf(1.f - zz, nn, zz * hj4[r]);
        hp[r] = (short)f2bfr(hj4[r]);
      }
      if (jj == 0) {
        *(short4v*)(hdst + n0) = hp;
        *(short4v*)(htsg + ((size_t)b * TT + t) * 128 + n0) = hp;
      }
      xr_c = xr_n; xz_c = xz_n; xn_c = xn_n;
      xr_n = xr_f; xz_n = xz_f; xn_n = xn_f;
      bar_lds();
    }
  } else {
    // ================= phase1 producer (chunk-major) =================
    __builtin_amdgcn_s_setprio(0);
    const int gi = blockIdx.x - 128;
    const int chunk = gi >> 6, b = gi & 63;
    const int t0 = chunk * 32;
    const int NT = (TT - t0 < 32) ? (TT - t0) : 32;
    ushort* Xl = pool;
    ushort* Yl = pool + 13568;
    ushort* St = pool;
    const ushort* w1b  = wts;
    const ushort* w2b  = wts + 32768;
    const ushort* w3b  = wts + 81920;
    const ushort* wihb = wts + 114688;
    const ushort* keyb = wts + 163840;
    const ushort* wgb  = wts + 167936;

    {
      const int tok = tid >> 4, l16 = tid & 15;
      const int tsrc = (tok < NT) ? tok : (NT - 1);
      const int gt = b * TT + t0 + tsrc;
      const int e = e_data[gt], a = a_data[gt];
      const float* qrow = qm + (size_t)e * 101;
      float qv[7];
#pragma unroll
      for (int i = 0; i < 7; ++i) {
        int s = l16 + 16 * i;
        qv[i] = (s < 101) ? qrow[s] : 0.f;
      }
      const float* sbase = semb + l16 * 8;
      float4v acc0 = {0,0,0,0}, acc1 = {0,0,0,0};
      float cnt = 0.f;
#pragma unroll
      for (int i = 0; i < 7; ++i) {
        unsigned long long bal = __ballot(qv[i] != 0.f);
        unsigned m = (unsigned)((bal >> (tid & 48)) & 0xFFFFull);
        cnt += (float)__popc(m);
        while (m) {
          int s = 16 * i + __builtin_ctz(m);
          m &= m - 1;
          acc0 += *(const float4v*)(sbase + s * 128);
          acc1 += *(const float4v*)(sbase + s * 128 + 4);
        }
      }
      float inv = 1.f / fmaxf(cnt, 1.f);
      ushort* xr = Xl + tok * XS + l16 * 8;
#pragma unroll
      for (int r = 0; r < 4; ++r) { xr[r] = f2bf(acc0[r] * inv); xr[4 + r] = f2bf(acc1[r] * inv); }
      const float* ee = eemb + (size_t)e * 128 + l16 * 8;
      const float* ae = aemb + a * 128 + l16 * 8;
#pragma unroll
      for (int r = 0; r < 8; ++r) { xr[128 + r] = f2bf(ee[r]); xr[256 + r] = f2bf(ae[r]); }
    }
    __syncthreads();

    if (tid < 32) {
      int tau = tid;
      if (tau < NT) {
        const ushort* xr = Xl + tau * XS + 128;
        const float* wv = Wp + 256;
        float a0 = bp[0], a1 = 0.f, a2 = 0.f, a3 = 0.f;
        for (int j = 0; j < 128; j += 4) {
          a0 = fmaf(wv[j],     bf2f(xr[j]),     a0);
          a1 = fmaf(wv[j + 1], bf2f(xr[j + 1]), a1);
          a2 = fmaf(wv[j + 2], bf2f(xr[j + 2]), a2);
          a3 = fmaf(wv[j + 3], bf2f(xr[j + 3]), a3);
        }
        c1b[b * TT + t0 + tau] = (a0 + a1) + (a2 + a3);
      }
    }

    short8v axA[12], axB[12];
#pragma unroll
    for (int i = 0; i < 12; ++i) {
      axA[i] = *(short8v*)(Xl + jj * XS + i * 32 + seg * 8);
      axB[i] = *(short8v*)(Xl + (16 + jj) * XS + i * 32 + seg * 8);
    }

    for (int T = w; T < 24; T += 8) {
      float4v dA = {0,0,0,0}, dB = {0,0,0,0};
      float bv;
      if (T < 8) {
        const ushort* Bp = w1b + (T * 16 + jj) * 256 + seg * 8;
        bv = b1[T * 16 + jj];
#pragma unroll
        for (int k = 0; k < 8; ++k) {
          short8v bw = *(const short8v*)(Bp + k * 32);
          dA = MFMA(axA[k], bw, dA, 0, 0, 0);
          dB = MFMA(axB[k], bw, dB, 0, 0, 0);
        }
      } else if (T < 16) {
        const ushort* Bp = w2b + ((T - 8) * 16 + jj) * 384 + seg * 8;
        bv = b2[(T - 8) * 16 + jj];
#pragma unroll
        for (int k = 0; k < 12; ++k) {
          short8v bw = *(const short8v*)(Bp + k * 32);
          dA = MFMA(axA[k], bw, dA, 0, 0, 0);
          dB = MFMA(axB[k], bw, dB, 0, 0, 0);
        }
      } else {
        const ushort* Bp = w3b + ((T - 16) * 16 + jj) * 256 + seg * 8;
        bv = b3[(T - 16) * 16 + jj];
#pragma unroll
        for (int k = 0; k < 8; ++k) {
          short8v bw = *(const short8v*)(Bp + k * 32);
          dA = MFMA(axA[4 + k], bw, dA, 0, 0, 0);
          dB = MFMA(axB[4 + k], bw, dB, 0, 0, 0);
        }
      }
#pragma unroll
      for (int r = 0; r < 4; ++r) {
        float yA = dA[r] + bv, yB = dB[r] + bv;
        Yl[(seg * 4 + r) * XS + T * 16 + jj]      = f2bf(yA > 0.f ? yA : 0.f);
        Yl[(16 + seg * 4 + r) * XS + T * 16 + jj] = f2bf(yB > 0.f ? yB : 0.f);
      }
    }
    __syncthreads();

    short8v ayA[12], ayB[12];
#pragma unroll
    for (int i = 0; i < 12; ++i) {
      ayA[i] = *(short8v*)(Yl + jj * XS + i * 32 + seg * 8);
      ayB[i] = *(short8v*)(Yl + (16 + jj) * XS + i * 32 + seg * 8);
    }
    if (tid >= 32 && tid < 64) {
      int tau = tid - 32;
      if (tau < NT) {
        const ushort* xr = Yl + tau * XS;
        const float* wv = Wp1 + 256;
        float a0 = bp1[0], a1 = 0.f, a2 = 0.f, a3 = 0.f;
        for (int j = 0; j < 128; j += 4) {
          a0 = fmaf(wv[j],     bf2f(xr[j]),     a0);
          a1 = fmaf(wv[j + 1], bf2f(xr[j + 1]), a1);
          a2 = fmaf(wv[j + 2], bf2f(xr[j + 2]), a2);
          a3 = fmaf(wv[j + 3], bf2f(xr[j + 3]), a3);
        }
        c2b[b * TT + t0 + tau] = (a0 + a1) + (a2 + a3);
      }
    }
    __syncthreads();

    for (int T = w; T < 42; T += 8) {
      const ushort* Bp; int ai;
      if (T < 24)      { Bp = wihb + (T * 16 + jj) * 128 + seg * 8;        ai = 8; }
      else if (T < 40) { Bp = wgb  + ((T - 24) * 16 + jj) * 128 + seg * 8; ai = 4; }
      else             { Bp = keyb + ((T - 40) * 16 + jj) * 128 + seg * 8; ai = 0; }
      float4v dA = {0,0,0,0}, dB = {0,0,0,0};
#pragma unroll
      for (int k = 0; k < 4; ++k) {
        short8v bw = *(const short8v*)(Bp + k * 32);
        dA = MFMA(ayA[ai + k], bw, dA, 0, 0, 0);
        dB = MFMA(ayB[ai + k], bw, dB, 0, 0, 0);
      }
      if (T < 40) {
        float bv = (T < 24) ? bih[T * 16 + jj]
                 : (T < 32) ? bg[(T - 24) * 16 + jj] : bgg[(T - 32) * 16 + jj];
        int col = (T < 24) ? (T * 16 + jj) : (384 + (T - 24) * 16 + jj);
#pragma unroll
        for (int r = 0; r < 4; ++r) {
          St[(seg * 4 + r) * SS + col]      = f2bf(dA[r] + bv);
          St[(16 + seg * 4 + r) * SS + col] = f2bf(dB[r] + bv);
        }
      } else {
#pragma unroll
        for (int r = 0; r < 4; ++r) {
          int tokA = seg * 4 + r, tokB = 16 + seg * 4 + r;
          if (tokA < NT)
            wallb[((size_t)(b * TT + t0 + tokA)) * 32 + (T - 40) * 16 + jj] = dA[r];
          if (tokB < NT)
            wallb[((size_t)(b * TT + t0 + tokB)) * 32 + (T - 40) * 16 + jj] = dB[r];
        }
      }
    }
    __syncthreads();

    {
      const int tok = tid >> 4, sg = tid & 15;
      if (tok < NT) {
        size_t gt = (size_t)b * TT + t0 + tok;
#pragma unroll
        for (int p = 0; p < 3; ++p)
          *(short8v*)(gxb + gt * 384 + sg * 24 + p * 8) = *(short8v*)(St + tok * SS + sg * 24 + p * 8);
#pragma unroll
        for (int p = 0; p < 2; ++p)
          *(short8v*)(xgx + gt * 256 + sg * 16 + p * 8) = *(short8v*)(St + tok * SS + 384 + sg * 16 + p * 8);
      }
    }
    __syncthreads();
    if (tid == 0)
      __hip_atomic_store(flags + chunk * 64 + b, 1, __ATOMIC_RELEASE, __HIP_MEMORY_SCOPE_AGENT);
  }
}

// ---------------------------------------------------------------------------
// combine v2: 256 blocks (4/batch), 16 lanes per tau, vector loads + DPP reduce
// ---------------------------------------------------------------------------
__global__ __launch_bounds__(256) void combine_k(
    const ushort* __restrict__ htsg, const ushort* __restrict__ htsm,
    const float* __restrict__ c1b, const float* __restrict__ c2b,
    const float* __restrict__ Wp, const float* __restrict__ Wp1,
    float* __restrict__ out)
{
  const int b = blockIdx.x >> 2, q = blockIdx.x & 3;
  const int tid = threadIdx.x;
  const int wv = tid >> 6, l = tid & 63, slot = l >> 4, e = l & 15;
  float wpg[8], wpm[8], vpg[8], vpm[8];
#pragma unroll
  for (int r = 0; r < 8; ++r) {
    wpg[r] = Wp[e * 8 + r];  wpm[r] = Wp[128 + e * 8 + r];
    vpg[r] = Wp1[e * 8 + r]; vpm[r] = Wp1[128 + e * 8 + r];
  }
  if (q == 0 && tid == 0) out[(size_t)b * TT] = 0.f;
  const int tbeg = q * 125;
  const int tend = (tbeg + 125 < TT - 1) ? (tbeg + 125) : (TT - 1);
  for (int tau = tbeg + wv * 4 + slot; tau < tend; tau += 16) {
    size_t base = ((size_t)b * TT + tau) * 128;
    short8v hg = *(const short8v*)(htsg + base + e * 8);
    short8v hm = *(const short8v*)(htsm + base + e * 8);
    float qa = 0.f, qb = 0.f;
#pragma unroll
    for (int r = 0; r < 8; ++r) {
      float g = bf2f((ushort)hg[r]), m = bf2f((ushort)hm[r]);
      qa = fmaf(g, wpg[r], fmaf(m, wpm[r], qa));
      qb = fmaf(g, vpg[r], fmaf(m, vpm[r], qb));
    }
    qa = rsum16(qa);
    qb = rsum16(qb);
    if (e == 0) {
      size_t idx = (size_t)b * TT + tau + 1;
      out[idx] = sigm(qa + c1b[idx]) * sigm(qb + c2b[idx]);
    }
  }
}

// ---------------------------------------------------------------------------
extern "C" void kernel_launch(void* const* d_in, const int* in_sizes, int n_in,
                              void* d_out, int out_size, void* d_ws, size_t ws_size,
                              hipStream_t stream) {
  (void)in_sizes; (void)n_in; (void)out_size; (void)ws_size;
  const int* a_data = (const int*)d_in[1];
  const int* e_data = (const int*)d_in[2];
  const float* qm   = (const float*)d_in[4];
  const float* semb = (const float*)d_in[5];
  const float* aemb = (const float*)d_in[6];
  const float* eemb = (const float*)d_in[7];
  const float* W1 = (const float*)d_in[8];   const float* b1 = (const float*)d_in[9];
  const float* W2 = (const float*)d_in[10];  const float* b2 = (const float*)d_in[11];
  const float* W3 = (const float*)d_in[12];  const float* b3 = (const float*)d_in[13];
  const float* key = (const float*)d_in[14];
  const float* Wih = (const float*)d_in[15]; const float* Whh = (const float*)d_in[16];
  const float* bih = (const float*)d_in[17]; const float* bhh = (const float*)d_in[18];
  const float* Wg  = (const float*)d_in[19]; const float* bg  = (const float*)d_in[20];
  const float* Wgg = (const float*)d_in[21]; const float* bgg = (const float*)d_in[22];
  const float* Wf  = (const float*)d_in[23]; const float* bf_ = (const float*)d_in[24];
  const float* Wp  = (const float*)d_in[25]; const float* bp  = (const float*)d_in[26];
  const float* Wp1 = (const float*)d_in[27]; const float* bp1 = (const float*)d_in[28];
  const float* h0v = (const float*)d_in[29]; const float* m0  = (const float*)d_in[30];

  char* ws = (char*)d_ws;
  ushort* gxb  = (ushort*)(ws + 0);
  ushort* xgx  = (ushort*)(ws + 24576000);
  float* wallb = (float*)(ws + 40960000);
  ushort* htsm = (ushort*)(ws + 45056000);
  ushort* htsg = (ushort*)(ws + 53248000);
  float* c1b   = (float*)(ws + 61440000);
  float* c2b   = (float*)(ws + 61568000);
  ushort* wts  = (ushort*)(ws + 61696000);
  int* flags   = (int*)(ws + 62097408);
  float* out = (float*)d_out;

  hipMemsetAsync(flags, 0, 1024 * sizeof(int), stream);
  conv_k<<<dim3(784), dim3(256), 0, stream>>>(W1, W2, W3, Wih, key, Wg, Wgg, wts);
  mega_k<<<dim3(1152), dim3(512), 0, stream>>>(
      a_data, e_data, qm, semb, aemb, eemb, b1, b2, b3, bih, bg, bgg,
      Wp, bp, Wp1, bp1, wts, Wf, bf_, Wg, Wgg, Whh, bhh, h0v, m0,
      gxb, xgx, wallb, c1b, c2b, htsm, htsg, flags);
  combine_k<<<dim3(256), dim3(256), 0, stream>>>(
      htsg, htsm, c1b, c2b, Wp, Wp1, out);
}